// Round 1
// 230.898 us; speedup vs baseline: 1.1559x; 1.1559x over previous
//
#include <hip/hip_runtime.h>
#include <hip/hip_bf16.h>
#include <math.h>

#define N_NODES 100000
#define N_EDGES 800000
#define IN_C 96
#define OUT_C 64
#define C4 (IN_C / 4)   // 24 float4 chunks per node
#define XPAD 104        // padded LDS row stride in bf16 elems
#define SCAN_B 512      // scan block width

typedef __attribute__((ext_vector_type(8))) short bf16x8;
typedef __attribute__((ext_vector_type(4))) float f32x4;

// bf16 helpers (manual, deterministic RNE)
__device__ __forceinline__ float bf2f(unsigned short h) {
    return __uint_as_float(((unsigned)h) << 16);
}
__device__ __forceinline__ unsigned short f2bf(float f) {
    unsigned u = __float_as_uint(f);
    unsigned r = 0x7FFFu + ((u >> 16) & 1u);
    return (unsigned short)((u + r) >> 16);
}
__device__ __forceinline__ unsigned pack2bf(float a, float b) {
    return (unsigned)f2bf(a) | ((unsigned)f2bf(b) << 16);
}
// packed csr entry: [src:17][w_bf15:15]  (w in (0,1] so bf16 sign bit is 0)
__device__ __forceinline__ float dec_w(unsigned p) {
    return __uint_as_float((p & 0x7FFFu) << 16);
}
__device__ __forceinline__ float lo_bf(unsigned v) { return __uint_as_float(v << 16); }
__device__ __forceinline__ float hi_bf(unsigned v) { return __uint_as_float(v & 0xFFFF0000u); }

// ================= CSR build =================

// count in-degree AND record each edge's within-node slot (the atomic's return
// value) so the fill pass needs no second atomic.
__global__ void count_kernel(const int* __restrict__ col, int* __restrict__ cnt,
                             unsigned short* __restrict__ eidx, int e) {
    int i = blockIdx.x * blockDim.x + threadIdx.x;
    if (i < e) {
        int idx = atomicAdd(&cnt[col[i]], 1);
        eidx[i] = (unsigned short)idx;
    }
}

// per-512-block sums
__global__ void scan_pass1_kernel(const int* __restrict__ cnt, int* __restrict__ partials, int n) {
    __shared__ int s[SCAN_B];
    int i = blockIdx.x * SCAN_B + threadIdx.x;
    int v = (i < n) ? cnt[i] : 0;
    s[threadIdx.x] = v;
    __syncthreads();
    for (int off = SCAN_B / 2; off > 0; off >>= 1) {
        if (threadIdx.x < off) s[threadIdx.x] += s[threadIdx.x + off];
        __syncthreads();
    }
    if (threadIdx.x == 0) partials[blockIdx.x] = s[0];
}

// fused scan2+scan3: every block redundantly scans the partials (nparts<=512),
// then scans its own 512 cnt elements; writes row_start/dinv (+total).
__global__ void scan23_kernel(const int* __restrict__ cnt, const int* __restrict__ partials,
                              int* __restrict__ row_start, float* __restrict__ dinv,
                              int n, int nparts) {
    __shared__ int ps[SCAN_B];
    __shared__ int es[SCAN_B];
    int t = threadIdx.x;

    // inclusive scan of partials
    int pv = (t < nparts) ? partials[t] : 0;
    ps[t] = pv;
    __syncthreads();
    int run = pv;
    for (int off = 1; off < SCAN_B; off <<= 1) {
        int tmp = (t >= off) ? ps[t - off] : 0;
        __syncthreads();
        run += tmp;
        ps[t] = run;
        __syncthreads();
    }
    int total = ps[nparts - 1];
    __syncthreads();
    ps[t] = run - pv;   // exclusive
    __syncthreads();
    int block_off = ps[blockIdx.x];

    // inclusive scan of this block's cnt elements
    int i = blockIdx.x * SCAN_B + t;
    int v = (i < n) ? cnt[i] : 0;
    es[t] = v;
    __syncthreads();
    int erun = v;
    for (int off = 1; off < SCAN_B; off <<= 1) {
        int tmp = (t >= off) ? es[t - off] : 0;
        __syncthreads();
        erun += tmp;
        es[t] = erun;
        __syncthreads();
    }
    if (i < n) {
        int start = block_off + erun - v;   // exclusive
        row_start[i] = start;
        dinv[i] = rsqrtf((float)v + 1.0f);
    }
    if (blockIdx.x == 0 && t == 0) row_start[n] = total;
}

// ================= fused: csr_fill + linear, interleaved 2:1 =================
// blockIdx%3 in {0,1} -> fill block (atomic-free: pos = row_start[c]+eidx[i]);
// blockIdx%3 == 2     -> linear block (MFMA x@W^T, W staged in LDS, x loaded
//                        global->reg directly: only 13.3KB LDS -> 8 blocks/CU).

__global__ void fill_linear_kernel(const int* __restrict__ row, const int* __restrict__ col,
                                   const float* __restrict__ dinv,
                                   const int* __restrict__ row_start,
                                   const unsigned short* __restrict__ eidx,
                                   unsigned* __restrict__ csr, int e,
                                   const float* __restrict__ x, const float* __restrict__ W,
                                   unsigned short* __restrict__ y, int n, int nb_lin) {
    __shared__ unsigned short wbf[64 * XPAD];

    int g = blockIdx.x / 3;
    int r3 = blockIdx.x - g * 3;
    if (r3 != 2) {
        int i = (g * 2 + r3) * 256 + threadIdx.x;
        if (i < e) {
            int r = row[i];
            int c = col[i];
            float w = dinv[r] * dinv[c];
            int pos = row_start[c] + (int)eidx[i];
            csr[pos] = ((unsigned)r << 15) | (unsigned)f2bf(w);
        }
        return;
    }
    if (g >= nb_lin) return;

    int tid = threadIdx.x;
    int lane = tid & 63;
    int wv = tid >> 6;
    int node0 = g * 64;

    // stage W only (13.3KB)
    for (int i = tid; i < 64 * C4; i += 256) {
        int o = i / C4;
        int c4 = i - o * C4;
        float4 v = ((const float4*)(W + (size_t)o * IN_C))[c4];
        uint2 pk;
        pk.x = pack2bf(v.x, v.y);
        pk.y = pack2bf(v.z, v.w);
        *(uint2*)&wbf[o * XPAD + c4 * 4] = pk;
    }
    __syncthreads();

    int l16 = lane & 15;
    int quad = lane >> 4;

    // A-row for this lane: loaded straight from global (f32 -> bf16, same RNE)
    int arow = node0 + wv * 16 + l16;
    const float* xr = x + (size_t)((arow < n) ? arow : 0) * IN_C + quad * 8;

    f32x4 acc0 = {0.f, 0.f, 0.f, 0.f};
    f32x4 acc1 = {0.f, 0.f, 0.f, 0.f};
    f32x4 acc2 = {0.f, 0.f, 0.f, 0.f};
    f32x4 acc3 = {0.f, 0.f, 0.f, 0.f};

#pragma unroll
    for (int kc = 0; kc < 3; ++kc) {
        float4 v0 = ((const float4*)(xr + kc * 32))[0];
        float4 v1 = ((const float4*)(xr + kc * 32))[1];
        union { bf16x8 v; unsigned u[4]; } au;
        au.u[0] = pack2bf(v0.x, v0.y);
        au.u[1] = pack2bf(v0.z, v0.w);
        au.u[2] = pack2bf(v1.x, v1.y);
        au.u[3] = pack2bf(v1.z, v1.w);
        bf16x8 a = au.v;
        bf16x8 b0 = *(const bf16x8*)&wbf[(0 * 16 + l16) * XPAD + kc * 32 + quad * 8];
        bf16x8 b1 = *(const bf16x8*)&wbf[(1 * 16 + l16) * XPAD + kc * 32 + quad * 8];
        bf16x8 b2 = *(const bf16x8*)&wbf[(2 * 16 + l16) * XPAD + kc * 32 + quad * 8];
        bf16x8 b3 = *(const bf16x8*)&wbf[(3 * 16 + l16) * XPAD + kc * 32 + quad * 8];
        acc0 = __builtin_amdgcn_mfma_f32_16x16x32_bf16(a, b0, acc0, 0, 0, 0);
        acc1 = __builtin_amdgcn_mfma_f32_16x16x32_bf16(a, b1, acc1, 0, 0, 0);
        acc2 = __builtin_amdgcn_mfma_f32_16x16x32_bf16(a, b2, acc2, 0, 0, 0);
        acc3 = __builtin_amdgcn_mfma_f32_16x16x32_bf16(a, b3, acc3, 0, 0, 0);
    }

#pragma unroll
    for (int r = 0; r < 4; ++r) {
        int node = node0 + wv * 16 + quad * 4 + r;
        if (node < n) {
            size_t base = (size_t)node * OUT_C + l16;
            y[base + 0]  = f2bf(acc0[r]);
            y[base + 16] = f2bf(acc1[r]);
            y[base + 32] = f2bf(acc2[r]);
            y[base + 48] = f2bf(acc3[r]);
        }
    }
}

// ================= gather hop: one wave per node, half-wave = edge parity =================
// 64 bf16 ch = 32 dwords; lane&31 = channel pair, lane>>5 = edge parity.
// Predicated 4-slot batch loop: invalid slot -> p=0 -> weight +0.0, src node 0
// (finite), contributes exactly 0. Removes the serial remainder round-trips.

template <bool FINAL>
__global__ void gather_kernel(const unsigned short* __restrict__ src,
                              unsigned short* __restrict__ dst_bf,
                              float* __restrict__ dst_f32,
                              const int* __restrict__ row_start, const unsigned* __restrict__ csr,
                              const float* __restrict__ dinv, const float* __restrict__ bias,
                              int n) {
    int node = blockIdx.x * (blockDim.x >> 6) + (threadIdx.x >> 6);
    if (node >= n) return;
    int lane = threadIdx.x & 63;
    int half = lane >> 5;
    int c = lane & 31;                       // channels 2c, 2c+1
    const unsigned* srcp = (const unsigned*)src;

    float e0a = 0.f, e0b = 0.f, e1a = 0.f, e1b = 0.f;
    float e2a = 0.f, e2b = 0.f, e3a = 0.f, e3b = 0.f;

    // self-loop (half 0 only)
    unsigned pv = srcp[(size_t)node * 32 + c];
    float s = dinv[node];
    float ss = s * s;
    if (half == 0) { e0a = ss * lo_bf(pv); e0b = ss * hi_bf(pv); }

    int beg = row_start[node];
    int end = row_start[node + 1];
    for (int j = beg + half; j < end; j += 8) {
        unsigned p0 = csr[j];
        unsigned p1 = (j + 2 < end) ? csr[j + 2] : 0u;
        unsigned p2 = (j + 4 < end) ? csr[j + 4] : 0u;
        unsigned p3 = (j + 6 < end) ? csr[j + 6] : 0u;
        unsigned v0 = srcp[(size_t)(p0 >> 15) * 32 + c];
        unsigned v1 = srcp[(size_t)(p1 >> 15) * 32 + c];
        unsigned v2 = srcp[(size_t)(p2 >> 15) * 32 + c];
        unsigned v3 = srcp[(size_t)(p3 >> 15) * 32 + c];
        float w0 = dec_w(p0), w1 = dec_w(p1), w2 = dec_w(p2), w3 = dec_w(p3);
        e0a += w0 * lo_bf(v0); e0b += w0 * hi_bf(v0);
        e1a += w1 * lo_bf(v1); e1b += w1 * hi_bf(v1);
        e2a += w2 * lo_bf(v2); e2b += w2 * hi_bf(v2);
        e3a += w3 * lo_bf(v3); e3b += w3 * hi_bf(v3);
    }
    float a0 = (e0a + e1a) + (e2a + e3a);
    float a1 = (e0b + e1b) + (e2b + e3b);
    a0 += __shfl_xor(a0, 32);
    a1 += __shfl_xor(a1, 32);

    if (FINAL) {
        float2 bb = ((const float2*)bias)[c];
        a0 = 1.0f / (1.0f + __expf(-(a0 + bb.x)));
        a1 = 1.0f / (1.0f + __expf(-(a1 + bb.y)));
        if (half == 0) ((float2*)dst_f32)[(size_t)node * 32 + c] = make_float2(a0, a1);
    } else {
        if (half == 0) ((unsigned*)dst_bf)[(size_t)node * 32 + c] = pack2bf(a0, a1);
    }
}

// ================= launch =================

static inline size_t align16(size_t x) { return (x + 15) & ~(size_t)15; }

extern "C" void kernel_launch(void* const* d_in, const int* in_sizes, int n_in,
                              void* d_out, int out_size, void* d_ws, size_t ws_size,
                              hipStream_t stream) {
    const float* x = (const float*)d_in[0];
    const int* edge_index = (const int*)d_in[1];
    const float* W = (const float*)d_in[2];
    const float* b = (const float*)d_in[3];
    float* out = (float*)d_out;

    const int N = N_NODES;
    const int E = in_sizes[1] / 2;

    const int* row = edge_index;        // source
    const int* col = edge_index + E;    // destination

    char* ws = (char*)d_ws;
    size_t off = 0;
    int* cnt = (int*)(ws + off);             off = align16(off + (size_t)N * 4);
    float* dinv = (float*)(ws + off);        off = align16(off + (size_t)N * 4);
    int* row_start = (int*)(ws + off);       off = align16(off + (size_t)(N + 1) * 4);
    int* partials = (int*)(ws + off);        off = align16(off + 512 * 4);
    unsigned* csr = (unsigned*)(ws + off);   off = align16(off + (size_t)E * 4);
    unsigned short* y0 = (unsigned short*)(ws + off); off = align16(off + (size_t)N * OUT_C * 2);
    unsigned short* y1 = (unsigned short*)(ws + off); off = align16(off + (size_t)N * OUT_C * 2);
    // eidx lifetime (count -> fill) is disjoint from y1 (gather1 -> gather2): alias.
    unsigned short* eidx = y1;

    const int B = 256;
    const int nb_e = (E + B - 1) / B;               // 3125
    const int nb_scan = (N + SCAN_B - 1) / SCAN_B;  // 196
    const int nb_lin = (N + 63) / 64;               // 1563
    int nbg = nb_lin;                                // groups of {2 fill, 1 linear}
    if (2 * nbg < nb_e) nbg = (nb_e + 1) / 2;

    // ---- CSR metadata ----
    hipMemsetAsync(cnt, 0, (size_t)N * 4, stream);
    count_kernel<<<nb_e, B, 0, stream>>>(col, cnt, eidx, E);
    scan_pass1_kernel<<<nb_scan, SCAN_B, 0, stream>>>(cnt, partials, N);
    scan23_kernel<<<nb_scan, SCAN_B, 0, stream>>>(cnt, partials, row_start, dinv, N, nb_scan);

    // ---- fused: csr_fill (atomic-free) + linear, interleaved 2:1 ----
    fill_linear_kernel<<<3 * nbg, B, 0, stream>>>(row, col, dinv, row_start, eidx, csr, E,
                                                  x, W, y0, N, nb_lin);

    // ---- hop 1 ----
    gather_kernel<false><<<(N + 3) / 4, B, 0, stream>>>(y0, y1, nullptr, row_start, csr, dinv, b, N);

    // ---- hop 2 + bias + sigmoid ----
    gather_kernel<true><<<(N + 3) / 4, B, 0, stream>>>(y1, nullptr, out, row_start, csr, dinv, b, N);
}

// Round 4
// 229.996 us; speedup vs baseline: 1.1604x; 1.0039x over previous
//
#include <hip/hip_runtime.h>
#include <hip/hip_bf16.h>
#include <math.h>

#define N_NODES 100000
#define N_EDGES 800000
#define IN_C 96
#define OUT_C 64
#define C4 (IN_C / 4)   // 24 float4 chunks per node
#define XPAD 104        // padded LDS row stride in bf16 elems
#define SCAN_B 512      // scan block width

typedef __attribute__((ext_vector_type(8))) short bf16x8;
typedef __attribute__((ext_vector_type(4))) float f32x4;

// bf16 helpers (manual, deterministic RNE)
__device__ __forceinline__ float bf2f(unsigned short h) {
    return __uint_as_float(((unsigned)h) << 16);
}
__device__ __forceinline__ unsigned short f2bf(float f) {
    unsigned u = __float_as_uint(f);
    unsigned r = 0x7FFFu + ((u >> 16) & 1u);
    return (unsigned short)((u + r) >> 16);
}
__device__ __forceinline__ unsigned pack2bf(float a, float b) {
    return (unsigned)f2bf(a) | ((unsigned)f2bf(b) << 16);
}
// packed csr entry: [src:17][w_bf15:15]  (w in (0,1] so bf16 sign bit is 0)
__device__ __forceinline__ float dec_w(unsigned p) {
    return __uint_as_float((p & 0x7FFFu) << 16);
}
__device__ __forceinline__ float lo_bf(unsigned v) { return __uint_as_float(v << 16); }
__device__ __forceinline__ float hi_bf(unsigned v) { return __uint_as_float(v & 0xFFFF0000u); }

// ================= CSR build =================

// count in-degree AND record each edge's within-node slot (the atomic's return
// value) so the fill pass needs no second atomic.
__global__ void count_kernel(const int* __restrict__ col, int* __restrict__ cnt,
                             unsigned short* __restrict__ eidx, int e) {
    int i = blockIdx.x * blockDim.x + threadIdx.x;
    if (i < e) {
        int idx = atomicAdd(&cnt[col[i]], 1);
        eidx[i] = (unsigned short)idx;
    }
}

// per-512-block sums
__global__ void scan_pass1_kernel(const int* __restrict__ cnt, int* __restrict__ partials, int n) {
    __shared__ int s[SCAN_B];
    int i = blockIdx.x * SCAN_B + threadIdx.x;
    int v = (i < n) ? cnt[i] : 0;
    s[threadIdx.x] = v;
    __syncthreads();
    for (int off = SCAN_B / 2; off > 0; off >>= 1) {
        if (threadIdx.x < off) s[threadIdx.x] += s[threadIdx.x + off];
        __syncthreads();
    }
    if (threadIdx.x == 0) partials[blockIdx.x] = s[0];
}

// fused scan2+scan3: every block redundantly scans the partials (nparts<=512),
// then scans its own 512 cnt elements; writes row_start/dinv (+total).
__global__ void scan23_kernel(const int* __restrict__ cnt, const int* __restrict__ partials,
                              int* __restrict__ row_start, float* __restrict__ dinv,
                              int n, int nparts) {
    __shared__ int ps[SCAN_B];
    __shared__ int es[SCAN_B];
    int t = threadIdx.x;

    int pv = (t < nparts) ? partials[t] : 0;
    ps[t] = pv;
    __syncthreads();
    int run = pv;
    for (int off = 1; off < SCAN_B; off <<= 1) {
        int tmp = (t >= off) ? ps[t - off] : 0;
        __syncthreads();
        run += tmp;
        ps[t] = run;
        __syncthreads();
    }
    int total = ps[nparts - 1];
    __syncthreads();
    ps[t] = run - pv;   // exclusive
    __syncthreads();
    int block_off = ps[blockIdx.x];

    int i = blockIdx.x * SCAN_B + t;
    int v = (i < n) ? cnt[i] : 0;
    es[t] = v;
    __syncthreads();
    int erun = v;
    for (int off = 1; off < SCAN_B; off <<= 1) {
        int tmp = (t >= off) ? es[t - off] : 0;
        __syncthreads();
        erun += tmp;
        es[t] = erun;
        __syncthreads();
    }
    if (i < n) {
        int start = block_off + erun - v;   // exclusive
        row_start[i] = start;
        dinv[i] = rsqrtf((float)v + 1.0f);
    }
    if (blockIdx.x == 0 && t == 0) row_start[n] = total;
}

// ================= fused: csr_fill + linear, interleaved 2:1 =================
// blockIdx%3 in {0,1} -> fill block (atomic-free: pos = row_start[c]+eidx[i]);
// blockIdx%3 == 2     -> linear block (MFMA x@W^T, W staged in LDS, x loaded
//                        global->reg directly: only 13.3KB LDS -> 8 blocks/CU).

__global__ void fill_linear_kernel(const int* __restrict__ row, const int* __restrict__ col,
                                   const float* __restrict__ dinv,
                                   const int* __restrict__ row_start,
                                   const unsigned short* __restrict__ eidx,
                                   unsigned* __restrict__ csr, int e,
                                   const float* __restrict__ x, const float* __restrict__ W,
                                   unsigned short* __restrict__ y, int n, int nb_lin) {
    __shared__ unsigned short wbf[64 * XPAD];

    int g = blockIdx.x / 3;
    int r3 = blockIdx.x - g * 3;
    if (r3 != 2) {
        int i = (g * 2 + r3) * 256 + threadIdx.x;
        if (i < e) {
            int r = row[i];
            int c = col[i];
            float w = dinv[r] * dinv[c];
            int pos = row_start[c] + (int)eidx[i];
            csr[pos] = ((unsigned)r << 15) | (unsigned)f2bf(w);
        }
        return;
    }
    if (g >= nb_lin) return;

    int tid = threadIdx.x;
    int lane = tid & 63;
    int wv = tid >> 6;
    int node0 = g * 64;

    // stage W only (13.3KB)
    for (int i = tid; i < 64 * C4; i += 256) {
        int o = i / C4;
        int c4 = i - o * C4;
        float4 v = ((const float4*)(W + (size_t)o * IN_C))[c4];
        uint2 pk;
        pk.x = pack2bf(v.x, v.y);
        pk.y = pack2bf(v.z, v.w);
        *(uint2*)&wbf[o * XPAD + c4 * 4] = pk;
    }
    __syncthreads();

    int l16 = lane & 15;
    int quad = lane >> 4;

    // A-row for this lane: loaded straight from global (f32 -> bf16, same RNE)
    int arow = node0 + wv * 16 + l16;
    const float* xr = x + (size_t)((arow < n) ? arow : 0) * IN_C + quad * 8;

    f32x4 acc0 = {0.f, 0.f, 0.f, 0.f};
    f32x4 acc1 = {0.f, 0.f, 0.f, 0.f};
    f32x4 acc2 = {0.f, 0.f, 0.f, 0.f};
    f32x4 acc3 = {0.f, 0.f, 0.f, 0.f};

#pragma unroll
    for (int kc = 0; kc < 3; ++kc) {
        float4 v0 = ((const float4*)(xr + kc * 32))[0];
        float4 v1 = ((const float4*)(xr + kc * 32))[1];
        union { bf16x8 v; unsigned u[4]; } au;
        au.u[0] = pack2bf(v0.x, v0.y);
        au.u[1] = pack2bf(v0.z, v0.w);
        au.u[2] = pack2bf(v1.x, v1.y);
        au.u[3] = pack2bf(v1.z, v1.w);
        bf16x8 a = au.v;
        bf16x8 b0 = *(const bf16x8*)&wbf[(0 * 16 + l16) * XPAD + kc * 32 + quad * 8];
        bf16x8 b1 = *(const bf16x8*)&wbf[(1 * 16 + l16) * XPAD + kc * 32 + quad * 8];
        bf16x8 b2 = *(const bf16x8*)&wbf[(2 * 16 + l16) * XPAD + kc * 32 + quad * 8];
        bf16x8 b3 = *(const bf16x8*)&wbf[(3 * 16 + l16) * XPAD + kc * 32 + quad * 8];
        acc0 = __builtin_amdgcn_mfma_f32_16x16x32_bf16(a, b0, acc0, 0, 0, 0);
        acc1 = __builtin_amdgcn_mfma_f32_16x16x32_bf16(a, b1, acc1, 0, 0, 0);
        acc2 = __builtin_amdgcn_mfma_f32_16x16x32_bf16(a, b2, acc2, 0, 0, 0);
        acc3 = __builtin_amdgcn_mfma_f32_16x16x32_bf16(a, b3, acc3, 0, 0, 0);
    }

#pragma unroll
    for (int r = 0; r < 4; ++r) {
        int node = node0 + wv * 16 + quad * 4 + r;
        if (node < n) {
            size_t base = (size_t)node * OUT_C + l16;
            y[base + 0]  = f2bf(acc0[r]);
            y[base + 16] = f2bf(acc1[r]);
            y[base + 32] = f2bf(acc2[r]);
            y[base + 48] = f2bf(acc3[r]);
        }
    }
}

// ================= gather hop: one wave per node, 8 lanes per edge =================
// lane = g*8 + c: group g in [0,8) handles edges j = beg + g (+8, +16...);
// lane c covers dwords 4c..4c+3 of the 128B node row (dwordx4 loads).
// 2 slots -> 16 edges in flight; >99% of nodes (Poisson deg ~8) finish in one
// iteration (2 serial round trips total). Invalid slot -> p=0 -> w=+0.0,
// src node 0 (finite), contributes exactly 0.
// Final 8-group reduction: 3 rounds of shfl_xor (8/16/32).

template <bool FINAL>
__global__ void gather_kernel(const unsigned short* __restrict__ src,
                              unsigned short* __restrict__ dst_bf,
                              float* __restrict__ dst_f32,
                              const int* __restrict__ row_start, const unsigned* __restrict__ csr,
                              const float* __restrict__ dinv, const float* __restrict__ bias,
                              int n) {
    int node = blockIdx.x * (blockDim.x >> 6) + (threadIdx.x >> 6);
    if (node >= n) return;
    int lane = threadIdx.x & 63;
    int g = lane >> 3;
    int c = lane & 7;
    const uint4* srcp = (const uint4*)src;

    int beg = row_start[node];
    int end = row_start[node + 1];

    // self row (all groups load the same 128B line; only group 0 weights it)
    uint4 sv = srcp[(size_t)node * 8 + c];
    float s = dinv[node];
    float wself = (g == 0) ? s * s : 0.0f;

    float a0[8], a1[8];
    a0[0] = wself * lo_bf(sv.x); a0[1] = wself * hi_bf(sv.x);
    a0[2] = wself * lo_bf(sv.y); a0[3] = wself * hi_bf(sv.y);
    a0[4] = wself * lo_bf(sv.z); a0[5] = wself * hi_bf(sv.z);
    a0[6] = wself * lo_bf(sv.w); a0[7] = wself * hi_bf(sv.w);
#pragma unroll
    for (int k = 0; k < 8; ++k) a1[k] = 0.f;

    for (int j0 = beg; j0 < end; j0 += 16) {
        int ja = j0 + g;
        int jb = ja + 8;
        unsigned p0 = (ja < end) ? csr[ja] : 0u;
        unsigned p1 = (jb < end) ? csr[jb] : 0u;
        uint4 v0 = srcp[(size_t)(p0 >> 15) * 8 + c];
        uint4 v1 = srcp[(size_t)(p1 >> 15) * 8 + c];
        float w0 = dec_w(p0), w1 = dec_w(p1);
        a0[0] += w0 * lo_bf(v0.x); a0[1] += w0 * hi_bf(v0.x);
        a0[2] += w0 * lo_bf(v0.y); a0[3] += w0 * hi_bf(v0.y);
        a0[4] += w0 * lo_bf(v0.z); a0[5] += w0 * hi_bf(v0.z);
        a0[6] += w0 * lo_bf(v0.w); a0[7] += w0 * hi_bf(v0.w);
        a1[0] += w1 * lo_bf(v1.x); a1[1] += w1 * hi_bf(v1.x);
        a1[2] += w1 * lo_bf(v1.y); a1[3] += w1 * hi_bf(v1.y);
        a1[4] += w1 * lo_bf(v1.z); a1[5] += w1 * hi_bf(v1.z);
        a1[6] += w1 * lo_bf(v1.w); a1[7] += w1 * hi_bf(v1.w);
    }

#pragma unroll
    for (int k = 0; k < 8; ++k) {
        float v = a0[k] + a1[k];
        v += __shfl_xor(v, 8);
        v += __shfl_xor(v, 16);
        v += __shfl_xor(v, 32);
        a0[k] = v;
    }

    if (g != 0) return;
    if (FINAL) {
        const float4* bp = (const float4*)bias;
        float4 b0 = bp[c * 2];
        float4 b1 = bp[c * 2 + 1];
        float4 o0, o1;
        o0.x = 1.0f / (1.0f + __expf(-(a0[0] + b0.x)));
        o0.y = 1.0f / (1.0f + __expf(-(a0[1] + b0.y)));
        o0.z = 1.0f / (1.0f + __expf(-(a0[2] + b0.z)));
        o0.w = 1.0f / (1.0f + __expf(-(a0[3] + b0.w)));
        o1.x = 1.0f / (1.0f + __expf(-(a0[4] + b1.x)));
        o1.y = 1.0f / (1.0f + __expf(-(a0[5] + b1.y)));
        o1.z = 1.0f / (1.0f + __expf(-(a0[6] + b1.z)));
        o1.w = 1.0f / (1.0f + __expf(-(a0[7] + b1.w)));
        ((float4*)dst_f32)[(size_t)node * 16 + c * 2] = o0;
        ((float4*)dst_f32)[(size_t)node * 16 + c * 2 + 1] = o1;
    } else {
        uint4 o;
        o.x = pack2bf(a0[0], a0[1]);
        o.y = pack2bf(a0[2], a0[3]);
        o.z = pack2bf(a0[4], a0[5]);
        o.w = pack2bf(a0[6], a0[7]);
        ((uint4*)dst_bf)[(size_t)node * 8 + c] = o;
    }
}

// ================= launch =================

static inline size_t align16(size_t x) { return (x + 15) & ~(size_t)15; }

extern "C" void kernel_launch(void* const* d_in, const int* in_sizes, int n_in,
                              void* d_out, int out_size, void* d_ws, size_t ws_size,
                              hipStream_t stream) {
    const float* x = (const float*)d_in[0];
    const int* edge_index = (const int*)d_in[1];
    const float* W = (const float*)d_in[2];
    const float* b = (const float*)d_in[3];
    float* out = (float*)d_out;

    const int N = N_NODES;
    const int E = in_sizes[1] / 2;

    const int* row = edge_index;        // source
    const int* col = edge_index + E;    // destination

    char* ws = (char*)d_ws;
    size_t off = 0;
    int* cnt = (int*)(ws + off);             off = align16(off + (size_t)N * 4);
    float* dinv = (float*)(ws + off);        off = align16(off + (size_t)N * 4);
    int* row_start = (int*)(ws + off);       off = align16(off + (size_t)(N + 1) * 4);
    int* partials = (int*)(ws + off);        off = align16(off + 512 * 4);
    unsigned* csr = (unsigned*)(ws + off);   off = align16(off + (size_t)E * 4);
    unsigned short* y0 = (unsigned short*)(ws + off); off = align16(off + (size_t)N * OUT_C * 2);
    unsigned short* y1 = (unsigned short*)(ws + off); off = align16(off + (size_t)N * OUT_C * 2);
    // eidx lifetime (count -> fill) is disjoint from y1 (gather1 -> gather2): alias.
    unsigned short* eidx = y1;

    const int B = 256;
    const int nb_e = (E + B - 1) / B;               // 3125
    const int nb_scan = (N + SCAN_B - 1) / SCAN_B;  // 196
    const int nb_lin = (N + 63) / 64;               // 1563
    int nbg = nb_lin;                                // groups of {2 fill, 1 linear}
    if (2 * nbg < nb_e) nbg = (nb_e + 1) / 2;

    // ---- CSR metadata ----
    hipMemsetAsync(cnt, 0, (size_t)N * 4, stream);
    count_kernel<<<nb_e, B, 0, stream>>>(col, cnt, eidx, E);
    scan_pass1_kernel<<<nb_scan, SCAN_B, 0, stream>>>(cnt, partials, N);
    scan23_kernel<<<nb_scan, SCAN_B, 0, stream>>>(cnt, partials, row_start, dinv, N, nb_scan);

    // ---- fused: csr_fill (atomic-free) + linear, interleaved 2:1 ----
    fill_linear_kernel<<<3 * nbg, B, 0, stream>>>(row, col, dinv, row_start, eidx, csr, E,
                                                  x, W, y0, N, nb_lin);

    // ---- hop 1 ----
    gather_kernel<false><<<(N + 3) / 4, B, 0, stream>>>(y0, y1, nullptr, row_start, csr, dinv, b, N);

    // ---- hop 2 + bias + sigmoid ----
    gather_kernel<true><<<(N + 3) / 4, B, 0, stream>>>(y1, nullptr, out, row_start, csr, dinv, b, N);
}

// Round 5
// 224.860 us; speedup vs baseline: 1.1869x; 1.0228x over previous
//
#include <hip/hip_runtime.h>
#include <hip/hip_bf16.h>
#include <math.h>

#define N_NODES 100000
#define N_EDGES 800000
#define IN_C 96
#define OUT_C 64
#define C4 (IN_C / 4)   // 24 float4 chunks per node
#define XPAD 104        // padded LDS row stride in bf16 elems
#define SCAN_B 512      // scan block width

typedef __attribute__((ext_vector_type(8))) short bf16x8;
typedef __attribute__((ext_vector_type(4))) float f32x4;

// bf16 helpers (manual, deterministic RNE)
__device__ __forceinline__ float bf2f(unsigned short h) {
    return __uint_as_float(((unsigned)h) << 16);
}
__device__ __forceinline__ unsigned short f2bf(float f) {
    unsigned u = __float_as_uint(f);
    unsigned r = 0x7FFFu + ((u >> 16) & 1u);
    return (unsigned short)((u + r) >> 16);
}
__device__ __forceinline__ unsigned pack2bf(float a, float b) {
    return (unsigned)f2bf(a) | ((unsigned)f2bf(b) << 16);
}
// packed csr entry: [src:17][w_bf15:15]  (w in (0,1] so bf16 sign bit is 0)
__device__ __forceinline__ float dec_w(unsigned p) {
    return __uint_as_float((p & 0x7FFFu) << 16);
}
__device__ __forceinline__ float lo_bf(unsigned v) { return __uint_as_float(v << 16); }
__device__ __forceinline__ float hi_bf(unsigned v) { return __uint_as_float(v & 0xFFFF0000u); }

// ================= CSR build =================

// count in-degree AND record each edge's within-node slot (the atomic's return
// value) so the fill pass needs no second atomic.
__global__ void count_kernel(const int* __restrict__ col, int* __restrict__ cnt,
                             unsigned short* __restrict__ eidx, int e) {
    int i = blockIdx.x * blockDim.x + threadIdx.x;
    if (i < e) {
        int idx = atomicAdd(&cnt[col[i]], 1);
        eidx[i] = (unsigned short)idx;
    }
}

// per-512-block sums
__global__ void scan_pass1_kernel(const int* __restrict__ cnt, int* __restrict__ partials, int n) {
    __shared__ int s[SCAN_B];
    int i = blockIdx.x * SCAN_B + threadIdx.x;
    int v = (i < n) ? cnt[i] : 0;
    s[threadIdx.x] = v;
    __syncthreads();
    for (int off = SCAN_B / 2; off > 0; off >>= 1) {
        if (threadIdx.x < off) s[threadIdx.x] += s[threadIdx.x + off];
        __syncthreads();
    }
    if (threadIdx.x == 0) partials[blockIdx.x] = s[0];
}

// fused scan2+scan3: every block redundantly scans the partials (nparts<=512),
// then scans its own 512 cnt elements; writes row_start/dinv (+total).
__global__ void scan23_kernel(const int* __restrict__ cnt, const int* __restrict__ partials,
                              int* __restrict__ row_start, float* __restrict__ dinv,
                              int n, int nparts) {
    __shared__ int ps[SCAN_B];
    __shared__ int es[SCAN_B];
    int t = threadIdx.x;

    int pv = (t < nparts) ? partials[t] : 0;
    ps[t] = pv;
    __syncthreads();
    int run = pv;
    for (int off = 1; off < SCAN_B; off <<= 1) {
        int tmp = (t >= off) ? ps[t - off] : 0;
        __syncthreads();
        run += tmp;
        ps[t] = run;
        __syncthreads();
    }
    int total = ps[nparts - 1];
    __syncthreads();
    ps[t] = run - pv;   // exclusive
    __syncthreads();
    int block_off = ps[blockIdx.x];

    int i = blockIdx.x * SCAN_B + t;
    int v = (i < n) ? cnt[i] : 0;
    es[t] = v;
    __syncthreads();
    int erun = v;
    for (int off = 1; off < SCAN_B; off <<= 1) {
        int tmp = (t >= off) ? es[t - off] : 0;
        __syncthreads();
        erun += tmp;
        es[t] = erun;
        __syncthreads();
    }
    if (i < n) {
        int start = block_off + erun - v;   // exclusive
        row_start[i] = start;
        dinv[i] = rsqrtf((float)v + 1.0f);
    }
    if (blockIdx.x == 0 && t == 0) row_start[n] = total;
}

// ================= fused: csr_fill + linear, interleaved 2:1 =================
// blockIdx%3 in {0,1} -> fill block (atomic-free: pos = row_start[c]+eidx[i]);
// blockIdx%3 == 2     -> linear block (MFMA x@W^T, W staged in LDS, x loaded
//                        global->reg directly: only 13.3KB LDS -> 8 blocks/CU).

__global__ void fill_linear_kernel(const int* __restrict__ row, const int* __restrict__ col,
                                   const float* __restrict__ dinv,
                                   const int* __restrict__ row_start,
                                   const unsigned short* __restrict__ eidx,
                                   unsigned* __restrict__ csr, int e,
                                   const float* __restrict__ x, const float* __restrict__ W,
                                   unsigned short* __restrict__ y, int n, int nb_lin) {
    __shared__ unsigned short wbf[64 * XPAD];

    int g = blockIdx.x / 3;
    int r3 = blockIdx.x - g * 3;
    if (r3 != 2) {
        int i = (g * 2 + r3) * 256 + threadIdx.x;
        if (i < e) {
            int r = row[i];
            int c = col[i];
            float w = dinv[r] * dinv[c];
            int pos = row_start[c] + (int)eidx[i];
            csr[pos] = ((unsigned)r << 15) | (unsigned)f2bf(w);
        }
        return;
    }
    if (g >= nb_lin) return;

    int tid = threadIdx.x;
    int lane = tid & 63;
    int wv = tid >> 6;
    int node0 = g * 64;

    // stage W only (13.3KB)
    for (int i = tid; i < 64 * C4; i += 256) {
        int o = i / C4;
        int c4 = i - o * C4;
        float4 v = ((const float4*)(W + (size_t)o * IN_C))[c4];
        uint2 pk;
        pk.x = pack2bf(v.x, v.y);
        pk.y = pack2bf(v.z, v.w);
        *(uint2*)&wbf[o * XPAD + c4 * 4] = pk;
    }
    __syncthreads();

    int l16 = lane & 15;
    int quad = lane >> 4;

    // A-row for this lane: loaded straight from global (f32 -> bf16, same RNE)
    int arow = node0 + wv * 16 + l16;
    const float* xr = x + (size_t)((arow < n) ? arow : 0) * IN_C + quad * 8;

    f32x4 acc0 = {0.f, 0.f, 0.f, 0.f};
    f32x4 acc1 = {0.f, 0.f, 0.f, 0.f};
    f32x4 acc2 = {0.f, 0.f, 0.f, 0.f};
    f32x4 acc3 = {0.f, 0.f, 0.f, 0.f};

#pragma unroll
    for (int kc = 0; kc < 3; ++kc) {
        float4 v0 = ((const float4*)(xr + kc * 32))[0];
        float4 v1 = ((const float4*)(xr + kc * 32))[1];
        union { bf16x8 v; unsigned u[4]; } au;
        au.u[0] = pack2bf(v0.x, v0.y);
        au.u[1] = pack2bf(v0.z, v0.w);
        au.u[2] = pack2bf(v1.x, v1.y);
        au.u[3] = pack2bf(v1.z, v1.w);
        bf16x8 a = au.v;
        bf16x8 b0 = *(const bf16x8*)&wbf[(0 * 16 + l16) * XPAD + kc * 32 + quad * 8];
        bf16x8 b1 = *(const bf16x8*)&wbf[(1 * 16 + l16) * XPAD + kc * 32 + quad * 8];
        bf16x8 b2 = *(const bf16x8*)&wbf[(2 * 16 + l16) * XPAD + kc * 32 + quad * 8];
        bf16x8 b3 = *(const bf16x8*)&wbf[(3 * 16 + l16) * XPAD + kc * 32 + quad * 8];
        acc0 = __builtin_amdgcn_mfma_f32_16x16x32_bf16(a, b0, acc0, 0, 0, 0);
        acc1 = __builtin_amdgcn_mfma_f32_16x16x32_bf16(a, b1, acc1, 0, 0, 0);
        acc2 = __builtin_amdgcn_mfma_f32_16x16x32_bf16(a, b2, acc2, 0, 0, 0);
        acc3 = __builtin_amdgcn_mfma_f32_16x16x32_bf16(a, b3, acc3, 0, 0, 0);
    }

#pragma unroll
    for (int r = 0; r < 4; ++r) {
        int node = node0 + wv * 16 + quad * 4 + r;
        if (node < n) {
            size_t base = (size_t)node * OUT_C + l16;
            y[base + 0]  = f2bf(acc0[r]);
            y[base + 16] = f2bf(acc1[r]);
            y[base + 32] = f2bf(acc2[r]);
            y[base + 48] = f2bf(acc3[r]);
        }
    }
}

// ================= gather hop: one wave per node, half-wave = edge parity =================
// 64 bf16 ch = 32 dwords; lane&31 = channel pair, lane>>5 = edge parity.
// Predicated 4-slot batches: 8 edges in flight per iteration, NO serial
// remainder loop (invalid slot -> p=0 -> w=+0.0, src node 0, contributes 0).
// deg<=8 nodes finish in ONE iteration; low VALU cost (2 ch/lane unpack).

template <bool FINAL>
__global__ void gather_kernel(const unsigned short* __restrict__ src,
                              unsigned short* __restrict__ dst_bf,
                              float* __restrict__ dst_f32,
                              const int* __restrict__ row_start, const unsigned* __restrict__ csr,
                              const float* __restrict__ dinv, const float* __restrict__ bias,
                              int n) {
    int node = blockIdx.x * (blockDim.x >> 6) + (threadIdx.x >> 6);
    if (node >= n) return;
    int lane = threadIdx.x & 63;
    int half = lane >> 5;
    int c = lane & 31;                       // channels 2c, 2c+1
    const unsigned* srcp = (const unsigned*)src;

    int beg = row_start[node];
    int end = row_start[node + 1];

    // self-loop (half 0 only)
    unsigned pv = srcp[(size_t)node * 32 + c];
    float s = dinv[node];
    float ss = (half == 0) ? s * s : 0.0f;

    float e0a = ss * lo_bf(pv), e0b = ss * hi_bf(pv);
    float e1a = 0.f, e1b = 0.f, e2a = 0.f, e2b = 0.f, e3a = 0.f, e3b = 0.f;

    for (int j = beg + half; j < end; j += 8) {
        unsigned p0 = csr[j];
        unsigned p1 = (j + 2 < end) ? csr[j + 2] : 0u;
        unsigned p2 = (j + 4 < end) ? csr[j + 4] : 0u;
        unsigned p3 = (j + 6 < end) ? csr[j + 6] : 0u;
        unsigned v0 = srcp[(size_t)(p0 >> 15) * 32 + c];
        unsigned v1 = srcp[(size_t)(p1 >> 15) * 32 + c];
        unsigned v2 = srcp[(size_t)(p2 >> 15) * 32 + c];
        unsigned v3 = srcp[(size_t)(p3 >> 15) * 32 + c];
        float w0 = dec_w(p0), w1 = dec_w(p1), w2 = dec_w(p2), w3 = dec_w(p3);
        e0a += w0 * lo_bf(v0); e0b += w0 * hi_bf(v0);
        e1a += w1 * lo_bf(v1); e1b += w1 * hi_bf(v1);
        e2a += w2 * lo_bf(v2); e2b += w2 * hi_bf(v2);
        e3a += w3 * lo_bf(v3); e3b += w3 * hi_bf(v3);
    }
    float a0 = (e0a + e1a) + (e2a + e3a);
    float a1 = (e0b + e1b) + (e2b + e3b);
    a0 += __shfl_xor(a0, 32);
    a1 += __shfl_xor(a1, 32);

    if (half != 0) return;
    if (FINAL) {
        float2 bb = ((const float2*)bias)[c];
        a0 = 1.0f / (1.0f + __expf(-(a0 + bb.x)));
        a1 = 1.0f / (1.0f + __expf(-(a1 + bb.y)));
        ((float2*)dst_f32)[(size_t)node * 32 + c] = make_float2(a0, a1);
    } else {
        ((unsigned*)dst_bf)[(size_t)node * 32 + c] = pack2bf(a0, a1);
    }
}

// ================= launch =================

static inline size_t align16(size_t x) { return (x + 15) & ~(size_t)15; }

extern "C" void kernel_launch(void* const* d_in, const int* in_sizes, int n_in,
                              void* d_out, int out_size, void* d_ws, size_t ws_size,
                              hipStream_t stream) {
    const float* x = (const float*)d_in[0];
    const int* edge_index = (const int*)d_in[1];
    const float* W = (const float*)d_in[2];
    const float* b = (const float*)d_in[3];
    float* out = (float*)d_out;

    const int N = N_NODES;
    const int E = in_sizes[1] / 2;

    const int* row = edge_index;        // source
    const int* col = edge_index + E;    // destination

    char* ws = (char*)d_ws;
    size_t off = 0;
    int* cnt = (int*)(ws + off);             off = align16(off + (size_t)N * 4);
    float* dinv = (float*)(ws + off);        off = align16(off + (size_t)N * 4);
    int* row_start = (int*)(ws + off);       off = align16(off + (size_t)(N + 1) * 4);
    int* partials = (int*)(ws + off);        off = align16(off + 512 * 4);
    unsigned* csr = (unsigned*)(ws + off);   off = align16(off + (size_t)E * 4);
    unsigned short* y0 = (unsigned short*)(ws + off); off = align16(off + (size_t)N * OUT_C * 2);
    unsigned short* y1 = (unsigned short*)(ws + off); off = align16(off + (size_t)N * OUT_C * 2);
    // eidx lifetime (count -> fill) is disjoint from y1 (gather1 -> gather2): alias.
    unsigned short* eidx = y1;

    const int B = 256;
    const int nb_e = (E + B - 1) / B;               // 3125
    const int nb_scan = (N + SCAN_B - 1) / SCAN_B;  // 196
    const int nb_lin = (N + 63) / 64;               // 1563
    int nbg = nb_lin;                                // groups of {2 fill, 1 linear}
    if (2 * nbg < nb_e) nbg = (nb_e + 1) / 2;

    // ---- CSR metadata ----
    hipMemsetAsync(cnt, 0, (size_t)N * 4, stream);
    count_kernel<<<nb_e, B, 0, stream>>>(col, cnt, eidx, E);
    scan_pass1_kernel<<<nb_scan, SCAN_B, 0, stream>>>(cnt, partials, N);
    scan23_kernel<<<nb_scan, SCAN_B, 0, stream>>>(cnt, partials, row_start, dinv, N, nb_scan);

    // ---- fused: csr_fill (atomic-free) + linear, interleaved 2:1 ----
    fill_linear_kernel<<<3 * nbg, B, 0, stream>>>(row, col, dinv, row_start, eidx, csr, E,
                                                  x, W, y0, N, nb_lin);

    // ---- hop 1 ----
    gather_kernel<false><<<(N + 3) / 4, B, 0, stream>>>(y0, y1, nullptr, row_start, csr, dinv, b, N);

    // ---- hop 2 + bias + sigmoid ----
    gather_kernel<true><<<(N + 3) / 4, B, 0, stream>>>(y1, nullptr, out, row_start, csr, dinv, b, N);
}

// Round 6
// 221.555 us; speedup vs baseline: 1.2046x; 1.0149x over previous
//
#include <hip/hip_runtime.h>
#include <hip/hip_bf16.h>
#include <math.h>

#define N_NODES 100000
#define N_EDGES 800000
#define IN_C 96
#define OUT_C 64
#define C4 (IN_C / 4)   // 24 float4 chunks per node
#define XPAD 104        // padded LDS row stride in bf16 elems
#define SCAN_B 512      // scan block width

typedef __attribute__((ext_vector_type(8))) short bf16x8;
typedef __attribute__((ext_vector_type(4))) float f32x4;

// bf16 helpers (manual, deterministic RNE)
__device__ __forceinline__ float bf2f(unsigned short h) {
    return __uint_as_float(((unsigned)h) << 16);
}
__device__ __forceinline__ unsigned short f2bf(float f) {
    unsigned u = __float_as_uint(f);
    unsigned r = 0x7FFFu + ((u >> 16) & 1u);
    return (unsigned short)((u + r) >> 16);
}
__device__ __forceinline__ unsigned pack2bf(float a, float b) {
    return (unsigned)f2bf(a) | ((unsigned)f2bf(b) << 16);
}
// packed csr entry: [src:17][w_bf15:15]  (w in (0,1] so bf16 sign bit is 0)
__device__ __forceinline__ float dec_w(unsigned p) {
    return __uint_as_float((p & 0x7FFFu) << 16);
}
__device__ __forceinline__ float lo_bf(unsigned v) { return __uint_as_float(v << 16); }
__device__ __forceinline__ float hi_bf(unsigned v) { return __uint_as_float(v & 0xFFFF0000u); }

// ================= CSR build =================

// count in-degree AND record each edge's within-node slot (the atomic's return
// value) so the fill pass needs no second atomic.
__global__ void count_kernel(const int* __restrict__ col, int* __restrict__ cnt,
                             unsigned short* __restrict__ eidx, int e) {
    int i = blockIdx.x * blockDim.x + threadIdx.x;
    if (i < e) {
        int idx = atomicAdd(&cnt[col[i]], 1);
        eidx[i] = (unsigned short)idx;
    }
}

// per-512-block sums
__global__ void scan_pass1_kernel(const int* __restrict__ cnt, int* __restrict__ partials, int n) {
    __shared__ int s[SCAN_B];
    int i = blockIdx.x * SCAN_B + threadIdx.x;
    int v = (i < n) ? cnt[i] : 0;
    s[threadIdx.x] = v;
    __syncthreads();
    for (int off = SCAN_B / 2; off > 0; off >>= 1) {
        if (threadIdx.x < off) s[threadIdx.x] += s[threadIdx.x + off];
        __syncthreads();
    }
    if (threadIdx.x == 0) partials[blockIdx.x] = s[0];
}

// fused scan2+scan3: every block redundantly scans the partials (nparts<=512),
// then scans its own 512 cnt elements; writes row_start/dinv (+total).
__global__ void scan23_kernel(const int* __restrict__ cnt, const int* __restrict__ partials,
                              int* __restrict__ row_start, float* __restrict__ dinv,
                              int n, int nparts) {
    __shared__ int ps[SCAN_B];
    __shared__ int es[SCAN_B];
    int t = threadIdx.x;

    int pv = (t < nparts) ? partials[t] : 0;
    ps[t] = pv;
    __syncthreads();
    int run = pv;
    for (int off = 1; off < SCAN_B; off <<= 1) {
        int tmp = (t >= off) ? ps[t - off] : 0;
        __syncthreads();
        run += tmp;
        ps[t] = run;
        __syncthreads();
    }
    int total = ps[nparts - 1];
    __syncthreads();
    ps[t] = run - pv;   // exclusive
    __syncthreads();
    int block_off = ps[blockIdx.x];

    int i = blockIdx.x * SCAN_B + t;
    int v = (i < n) ? cnt[i] : 0;
    es[t] = v;
    __syncthreads();
    int erun = v;
    for (int off = 1; off < SCAN_B; off <<= 1) {
        int tmp = (t >= off) ? es[t - off] : 0;
        __syncthreads();
        erun += tmp;
        es[t] = erun;
        __syncthreads();
    }
    if (i < n) {
        int start = block_off + erun - v;   // exclusive
        row_start[i] = start;
        dinv[i] = rsqrtf((float)v + 1.0f);
    }
    if (blockIdx.x == 0 && t == 0) row_start[n] = total;
}

// ================= fused: csr_fill + linear, interleaved 2:1 =================
// blockIdx%3 in {0,1} -> fill block (atomic-free: pos = row_start[c]+eidx[i]);
// blockIdx%3 == 2     -> linear block (MFMA x@W^T, W staged in LDS, x loaded
//                        global->reg directly: only 13.3KB LDS -> 8 blocks/CU).

__global__ void fill_linear_kernel(const int* __restrict__ row, const int* __restrict__ col,
                                   const float* __restrict__ dinv,
                                   const int* __restrict__ row_start,
                                   const unsigned short* __restrict__ eidx,
                                   unsigned* __restrict__ csr, int e,
                                   const float* __restrict__ x, const float* __restrict__ W,
                                   unsigned short* __restrict__ y, int n, int nb_lin) {
    __shared__ unsigned short wbf[64 * XPAD];

    int g = blockIdx.x / 3;
    int r3 = blockIdx.x - g * 3;
    if (r3 != 2) {
        int i = (g * 2 + r3) * 256 + threadIdx.x;
        if (i < e) {
            int r = row[i];
            int c = col[i];
            float w = dinv[r] * dinv[c];
            int pos = row_start[c] + (int)eidx[i];
            csr[pos] = ((unsigned)r << 15) | (unsigned)f2bf(w);
        }
        return;
    }
    if (g >= nb_lin) return;

    int tid = threadIdx.x;
    int lane = tid & 63;
    int wv = tid >> 6;
    int node0 = g * 64;

    // stage W only (13.3KB)
    for (int i = tid; i < 64 * C4; i += 256) {
        int o = i / C4;
        int c4 = i - o * C4;
        float4 v = ((const float4*)(W + (size_t)o * IN_C))[c4];
        uint2 pk;
        pk.x = pack2bf(v.x, v.y);
        pk.y = pack2bf(v.z, v.w);
        *(uint2*)&wbf[o * XPAD + c4 * 4] = pk;
    }
    __syncthreads();

    int l16 = lane & 15;
    int quad = lane >> 4;

    // A-row for this lane: loaded straight from global (f32 -> bf16, same RNE)
    int arow = node0 + wv * 16 + l16;
    const float* xr = x + (size_t)((arow < n) ? arow : 0) * IN_C + quad * 8;

    f32x4 acc0 = {0.f, 0.f, 0.f, 0.f};
    f32x4 acc1 = {0.f, 0.f, 0.f, 0.f};
    f32x4 acc2 = {0.f, 0.f, 0.f, 0.f};
    f32x4 acc3 = {0.f, 0.f, 0.f, 0.f};

#pragma unroll
    for (int kc = 0; kc < 3; ++kc) {
        float4 v0 = ((const float4*)(xr + kc * 32))[0];
        float4 v1 = ((const float4*)(xr + kc * 32))[1];
        union { bf16x8 v; unsigned u[4]; } au;
        au.u[0] = pack2bf(v0.x, v0.y);
        au.u[1] = pack2bf(v0.z, v0.w);
        au.u[2] = pack2bf(v1.x, v1.y);
        au.u[3] = pack2bf(v1.z, v1.w);
        bf16x8 a = au.v;
        bf16x8 b0 = *(const bf16x8*)&wbf[(0 * 16 + l16) * XPAD + kc * 32 + quad * 8];
        bf16x8 b1 = *(const bf16x8*)&wbf[(1 * 16 + l16) * XPAD + kc * 32 + quad * 8];
        bf16x8 b2 = *(const bf16x8*)&wbf[(2 * 16 + l16) * XPAD + kc * 32 + quad * 8];
        bf16x8 b3 = *(const bf16x8*)&wbf[(3 * 16 + l16) * XPAD + kc * 32 + quad * 8];
        acc0 = __builtin_amdgcn_mfma_f32_16x16x32_bf16(a, b0, acc0, 0, 0, 0);
        acc1 = __builtin_amdgcn_mfma_f32_16x16x32_bf16(a, b1, acc1, 0, 0, 0);
        acc2 = __builtin_amdgcn_mfma_f32_16x16x32_bf16(a, b2, acc2, 0, 0, 0);
        acc3 = __builtin_amdgcn_mfma_f32_16x16x32_bf16(a, b3, acc3, 0, 0, 0);
    }

#pragma unroll
    for (int r = 0; r < 4; ++r) {
        int node = node0 + wv * 16 + quad * 4 + r;
        if (node < n) {
            size_t base = (size_t)node * OUT_C + l16;
            y[base + 0]  = f2bf(acc0[r]);
            y[base + 16] = f2bf(acc1[r]);
            y[base + 32] = f2bf(acc2[r]);
            y[base + 48] = f2bf(acc3[r]);
        }
    }
}

// ================= gather hop: one wave per node, half-wave = edge parity =================
// 64 bf16 ch = 32 dwords; lane&31 = channel pair, lane>>5 = edge parity.
// 8 predicated slots per half-wave = 16 edges in flight per iteration.
// All 8 csr addresses derive from beg (one round trip), then 8 dependent src
// row loads (second round trip): deg<=16 nodes (99.7% at Poisson-8) finish in
// 3 total serial round trips. Invalid slot -> p=0 -> w=+0.0, src node 0,
// contributes exactly 0. Slots share 4 accumulator pairs (k&3).

template <bool FINAL>
__global__ void gather_kernel(const unsigned short* __restrict__ src,
                              unsigned short* __restrict__ dst_bf,
                              float* __restrict__ dst_f32,
                              const int* __restrict__ row_start, const unsigned* __restrict__ csr,
                              const float* __restrict__ dinv, const float* __restrict__ bias,
                              int n) {
    int node = blockIdx.x * (blockDim.x >> 6) + (threadIdx.x >> 6);
    if (node >= n) return;
    int lane = threadIdx.x & 63;
    int half = lane >> 5;
    int c = lane & 31;                       // channels 2c, 2c+1
    const unsigned* srcp = (const unsigned*)src;

    int beg = row_start[node];
    int end = row_start[node + 1];

    // self-loop (half 0 only)
    unsigned pv = srcp[(size_t)node * 32 + c];
    float s = dinv[node];
    float ss = (half == 0) ? s * s : 0.0f;

    float e0a = ss * lo_bf(pv), e0b = ss * hi_bf(pv);
    float e1a = 0.f, e1b = 0.f, e2a = 0.f, e2b = 0.f, e3a = 0.f, e3b = 0.f;

    for (int j = beg + half; j < end; j += 16) {
        unsigned p0 = csr[j];
        unsigned p1 = (j + 2  < end) ? csr[j + 2]  : 0u;
        unsigned p2 = (j + 4  < end) ? csr[j + 4]  : 0u;
        unsigned p3 = (j + 6  < end) ? csr[j + 6]  : 0u;
        unsigned p4 = (j + 8  < end) ? csr[j + 8]  : 0u;
        unsigned p5 = (j + 10 < end) ? csr[j + 10] : 0u;
        unsigned p6 = (j + 12 < end) ? csr[j + 12] : 0u;
        unsigned p7 = (j + 14 < end) ? csr[j + 14] : 0u;
        unsigned v0 = srcp[(size_t)(p0 >> 15) * 32 + c];
        unsigned v1 = srcp[(size_t)(p1 >> 15) * 32 + c];
        unsigned v2 = srcp[(size_t)(p2 >> 15) * 32 + c];
        unsigned v3 = srcp[(size_t)(p3 >> 15) * 32 + c];
        unsigned v4 = srcp[(size_t)(p4 >> 15) * 32 + c];
        unsigned v5 = srcp[(size_t)(p5 >> 15) * 32 + c];
        unsigned v6 = srcp[(size_t)(p6 >> 15) * 32 + c];
        unsigned v7 = srcp[(size_t)(p7 >> 15) * 32 + c];
        float w0 = dec_w(p0), w1 = dec_w(p1), w2 = dec_w(p2), w3 = dec_w(p3);
        float w4 = dec_w(p4), w5 = dec_w(p5), w6 = dec_w(p6), w7 = dec_w(p7);
        e0a += w0 * lo_bf(v0); e0b += w0 * hi_bf(v0);
        e1a += w1 * lo_bf(v1); e1b += w1 * hi_bf(v1);
        e2a += w2 * lo_bf(v2); e2b += w2 * hi_bf(v2);
        e3a += w3 * lo_bf(v3); e3b += w3 * hi_bf(v3);
        e0a += w4 * lo_bf(v4); e0b += w4 * hi_bf(v4);
        e1a += w5 * lo_bf(v5); e1b += w5 * hi_bf(v5);
        e2a += w6 * lo_bf(v6); e2b += w6 * hi_bf(v6);
        e3a += w7 * lo_bf(v7); e3b += w7 * hi_bf(v7);
    }
    float a0 = (e0a + e1a) + (e2a + e3a);
    float a1 = (e0b + e1b) + (e2b + e3b);
    a0 += __shfl_xor(a0, 32);
    a1 += __shfl_xor(a1, 32);

    if (half != 0) return;
    if (FINAL) {
        float2 bb = ((const float2*)bias)[c];
        a0 = 1.0f / (1.0f + __expf(-(a0 + bb.x)));
        a1 = 1.0f / (1.0f + __expf(-(a1 + bb.y)));
        ((float2*)dst_f32)[(size_t)node * 32 + c] = make_float2(a0, a1);
    } else {
        ((unsigned*)dst_bf)[(size_t)node * 32 + c] = pack2bf(a0, a1);
    }
}

// ================= launch =================

static inline size_t align16(size_t x) { return (x + 15) & ~(size_t)15; }

extern "C" void kernel_launch(void* const* d_in, const int* in_sizes, int n_in,
                              void* d_out, int out_size, void* d_ws, size_t ws_size,
                              hipStream_t stream) {
    const float* x = (const float*)d_in[0];
    const int* edge_index = (const int*)d_in[1];
    const float* W = (const float*)d_in[2];
    const float* b = (const float*)d_in[3];
    float* out = (float*)d_out;

    const int N = N_NODES;
    const int E = in_sizes[1] / 2;

    const int* row = edge_index;        // source
    const int* col = edge_index + E;    // destination

    char* ws = (char*)d_ws;
    size_t off = 0;
    int* cnt = (int*)(ws + off);             off = align16(off + (size_t)N * 4);
    float* dinv = (float*)(ws + off);        off = align16(off + (size_t)N * 4);
    int* row_start = (int*)(ws + off);       off = align16(off + (size_t)(N + 1) * 4);
    int* partials = (int*)(ws + off);        off = align16(off + 512 * 4);
    unsigned* csr = (unsigned*)(ws + off);   off = align16(off + (size_t)E * 4);
    unsigned short* y0 = (unsigned short*)(ws + off); off = align16(off + (size_t)N * OUT_C * 2);
    unsigned short* y1 = (unsigned short*)(ws + off); off = align16(off + (size_t)N * OUT_C * 2);
    // eidx lifetime (count -> fill) is disjoint from y1 (gather1 -> gather2): alias.
    unsigned short* eidx = y1;

    const int B = 256;
    const int nb_e = (E + B - 1) / B;               // 3125
    const int nb_scan = (N + SCAN_B - 1) / SCAN_B;  // 196
    const int nb_lin = (N + 63) / 64;               // 1563
    int nbg = nb_lin;                                // groups of {2 fill, 1 linear}
    if (2 * nbg < nb_e) nbg = (nb_e + 1) / 2;

    // ---- CSR metadata ----
    hipMemsetAsync(cnt, 0, (size_t)N * 4, stream);
    count_kernel<<<nb_e, B, 0, stream>>>(col, cnt, eidx, E);
    scan_pass1_kernel<<<nb_scan, SCAN_B, 0, stream>>>(cnt, partials, N);
    scan23_kernel<<<nb_scan, SCAN_B, 0, stream>>>(cnt, partials, row_start, dinv, N, nb_scan);

    // ---- fused: csr_fill (atomic-free) + linear, interleaved 2:1 ----
    fill_linear_kernel<<<3 * nbg, B, 0, stream>>>(row, col, dinv, row_start, eidx, csr, E,
                                                  x, W, y0, N, nb_lin);

    // ---- hop 1 ----
    gather_kernel<false><<<(N + 3) / 4, B, 0, stream>>>(y0, y1, nullptr, row_start, csr, dinv, b, N);

    // ---- hop 2 + bias + sigmoid ----
    gather_kernel<true><<<(N + 3) / 4, B, 0, stream>>>(y1, nullptr, out, row_start, csr, dinv, b, N);
}

// Round 8
// 209.989 us; speedup vs baseline: 1.2709x; 1.0551x over previous
//
#include <hip/hip_runtime.h>
#include <hip/hip_bf16.h>
#include <math.h>

#define N_NODES 100000
#define N_EDGES 800000
#define IN_C 96
#define OUT_C 64
#define C4 (IN_C / 4)   // 24 float4 chunks per node
#define XPAD 104        // padded LDS row stride in bf16 elems
#define SCAN_B 512      // scan block width

typedef __attribute__((ext_vector_type(8))) short bf16x8;
typedef __attribute__((ext_vector_type(4))) float f32x4;

// bf16 helpers (manual, deterministic RNE)
__device__ __forceinline__ unsigned short f2bf(float f) {
    unsigned u = __float_as_uint(f);
    unsigned r = 0x7FFFu + ((u >> 16) & 1u);
    return (unsigned short)((u + r) >> 16);
}
__device__ __forceinline__ unsigned pack2bf(float a, float b) {
    return (unsigned)f2bf(a) | ((unsigned)f2bf(b) << 16);
}
// packed csr entry: [src:17][w_bf15:15]  (w in (0,1] so bf16 sign bit is 0)
__device__ __forceinline__ float dec_w(unsigned p) {
    return __uint_as_float((p & 0x7FFFu) << 16);
}
__device__ __forceinline__ float lo_bf(unsigned v) { return __uint_as_float(v << 16); }
__device__ __forceinline__ float hi_bf(unsigned v) { return __uint_as_float(v & 0xFFFF0000u); }

// ================= CSR build =================

// count in-degree AND record each edge's within-node slot (the atomic's return
// value) so the fill pass needs no second atomic.
__global__ void count_kernel(const int* __restrict__ col, int* __restrict__ cnt,
                             unsigned short* __restrict__ eidx, int e) {
    int i = blockIdx.x * blockDim.x + threadIdx.x;
    if (i < e) {
        int idx = atomicAdd(&cnt[col[i]], 1);
        eidx[i] = (unsigned short)idx;
    }
}

// per-512-block sums
__global__ void scan_pass1_kernel(const int* __restrict__ cnt, int* __restrict__ partials, int n) {
    __shared__ int s[SCAN_B];
    int i = blockIdx.x * SCAN_B + threadIdx.x;
    int v = (i < n) ? cnt[i] : 0;
    s[threadIdx.x] = v;
    __syncthreads();
    for (int off = SCAN_B / 2; off > 0; off >>= 1) {
        if (threadIdx.x < off) s[threadIdx.x] += s[threadIdx.x + off];
        __syncthreads();
    }
    if (threadIdx.x == 0) partials[blockIdx.x] = s[0];
}

// fused scan2+scan3: every block redundantly scans the partials (nparts<=512),
// then scans its own 512 cnt elements; writes row_start/dinv (+total).
__global__ void scan23_kernel(const int* __restrict__ cnt, const int* __restrict__ partials,
                              int* __restrict__ row_start, float* __restrict__ dinv,
                              int n, int nparts) {
    __shared__ int ps[SCAN_B];
    __shared__ int es[SCAN_B];
    int t = threadIdx.x;

    int pv = (t < nparts) ? partials[t] : 0;
    ps[t] = pv;
    __syncthreads();
    int run = pv;
    for (int off = 1; off < SCAN_B; off <<= 1) {
        int tmp = (t >= off) ? ps[t - off] : 0;
        __syncthreads();
        run += tmp;
        ps[t] = run;
        __syncthreads();
    }
    int total = ps[nparts - 1];
    __syncthreads();
    ps[t] = run - pv;   // exclusive
    __syncthreads();
    int block_off = ps[blockIdx.x];

    int i = blockIdx.x * SCAN_B + t;
    int v = (i < n) ? cnt[i] : 0;
    es[t] = v;
    __syncthreads();
    int erun = v;
    for (int off = 1; off < SCAN_B; off <<= 1) {
        int tmp = (t >= off) ? es[t - off] : 0;
        __syncthreads();
        erun += tmp;
        es[t] = erun;
        __syncthreads();
    }
    if (i < n) {
        int start = block_off + erun - v;   // exclusive
        row_start[i] = start;
        dinv[i] = rsqrtf((float)v + 1.0f);
    }
    if (blockIdx.x == 0 && t == 0) row_start[n] = total;
}

// ================= fused: csr_fill + linear, interleaved 2:1 =================
// blockIdx%3 in {0,1} -> fill block (atomic-free: pos = row_start[c]+eidx[i]);
// blockIdx%3 == 2     -> linear block (MFMA x@W^T, W staged in LDS, x loaded
//                        global->reg directly: only 13.3KB LDS -> 8 blocks/CU).

__global__ void fill_linear_kernel(const int* __restrict__ row, const int* __restrict__ col,
                                   const float* __restrict__ dinv,
                                   const int* __restrict__ row_start,
                                   const unsigned short* __restrict__ eidx,
                                   unsigned* __restrict__ csr, int e,
                                   const float* __restrict__ x, const float* __restrict__ W,
                                   unsigned short* __restrict__ y, int n, int nb_lin) {
    __shared__ unsigned short wbf[64 * XPAD];

    int g = blockIdx.x / 3;
    int r3 = blockIdx.x - g * 3;
    if (r3 != 2) {
        int i = (g * 2 + r3) * 256 + threadIdx.x;
        if (i < e) {
            int r = row[i];
            int c = col[i];
            float w = dinv[r] * dinv[c];
            int pos = row_start[c] + (int)eidx[i];
            csr[pos] = ((unsigned)r << 15) | (unsigned)f2bf(w);
        }
        return;
    }
    if (g >= nb_lin) return;

    int tid = threadIdx.x;
    int lane = tid & 63;
    int wv = tid >> 6;
    int node0 = g * 64;

    // stage W only (13.3KB)
    for (int i = tid; i < 64 * C4; i += 256) {
        int o = i / C4;
        int c4 = i - o * C4;
        float4 v = ((const float4*)(W + (size_t)o * IN_C))[c4];
        uint2 pk;
        pk.x = pack2bf(v.x, v.y);
        pk.y = pack2bf(v.z, v.w);
        *(uint2*)&wbf[o * XPAD + c4 * 4] = pk;
    }
    __syncthreads();

    int l16 = lane & 15;
    int quad = lane >> 4;

    // A-row for this lane: loaded straight from global (f32 -> bf16, same RNE)
    int arow = node0 + wv * 16 + l16;
    const float* xr = x + (size_t)((arow < n) ? arow : 0) * IN_C + quad * 8;

    f32x4 acc0 = {0.f, 0.f, 0.f, 0.f};
    f32x4 acc1 = {0.f, 0.f, 0.f, 0.f};
    f32x4 acc2 = {0.f, 0.f, 0.f, 0.f};
    f32x4 acc3 = {0.f, 0.f, 0.f, 0.f};

#pragma unroll
    for (int kc = 0; kc < 3; ++kc) {
        float4 v0 = ((const float4*)(xr + kc * 32))[0];
        float4 v1 = ((const float4*)(xr + kc * 32))[1];
        union { bf16x8 v; unsigned u[4]; } au;
        au.u[0] = pack2bf(v0.x, v0.y);
        au.u[1] = pack2bf(v0.z, v0.w);
        au.u[2] = pack2bf(v1.x, v1.y);
        au.u[3] = pack2bf(v1.z, v1.w);
        bf16x8 a = au.v;
        bf16x8 b0 = *(const bf16x8*)&wbf[(0 * 16 + l16) * XPAD + kc * 32 + quad * 8];
        bf16x8 b1 = *(const bf16x8*)&wbf[(1 * 16 + l16) * XPAD + kc * 32 + quad * 8];
        bf16x8 b2 = *(const bf16x8*)&wbf[(2 * 16 + l16) * XPAD + kc * 32 + quad * 8];
        bf16x8 b3 = *(const bf16x8*)&wbf[(3 * 16 + l16) * XPAD + kc * 32 + quad * 8];
        acc0 = __builtin_amdgcn_mfma_f32_16x16x32_bf16(a, b0, acc0, 0, 0, 0);
        acc1 = __builtin_amdgcn_mfma_f32_16x16x32_bf16(a, b1, acc1, 0, 0, 0);
        acc2 = __builtin_amdgcn_mfma_f32_16x16x32_bf16(a, b2, acc2, 0, 0, 0);
        acc3 = __builtin_amdgcn_mfma_f32_16x16x32_bf16(a, b3, acc3, 0, 0, 0);
    }

#pragma unroll
    for (int r = 0; r < 4; ++r) {
        int node = node0 + wv * 16 + quad * 4 + r;
        if (node < n) {
            size_t base = (size_t)node * OUT_C + l16;
            y[base + 0]  = f2bf(acc0[r]);
            y[base + 16] = f2bf(acc1[r]);
            y[base + 32] = f2bf(acc2[r]);
            y[base + 48] = f2bf(acc3[r]);
        }
    }
}

// ================= gather hop: 32 lanes per node, 2 nodes per wave =================
// Lane c (0..31) of each 32-lane group owns channel pair 2c/2c+1 of its node.
// 16 predicated slots per iteration (invalid slot -> p=0 -> w=+0.0, src node 0,
// contributes exactly 0): deg<=16 (99.7% at Poisson-8) finishes in one
// iteration. One instruction stream serves TWO nodes (vs R6's one) -> per-node
// VALU/load issue halves; no parity split, no cross-half shuffle, no write mask.

template <bool FINAL>
__global__ void gather_kernel(const unsigned short* __restrict__ src,
                              unsigned short* __restrict__ dst_bf,
                              float* __restrict__ dst_f32,
                              const int* __restrict__ row_start, const unsigned* __restrict__ csr,
                              const float* __restrict__ dinv, const float* __restrict__ bias,
                              int n) {
    int node = blockIdx.x * (blockDim.x >> 5) + (threadIdx.x >> 5);
    if (node >= n) return;
    int c = threadIdx.x & 31;                // channels 2c, 2c+1
    const unsigned* srcp = (const unsigned*)src;

    int beg = row_start[node];
    int end = row_start[node + 1];

    // self-loop
    unsigned pv = srcp[(size_t)node * 32 + c];
    float s = dinv[node];
    float ss = s * s;

    float e0a = ss * lo_bf(pv), e0b = ss * hi_bf(pv);
    float e1a = 0.f, e1b = 0.f, e2a = 0.f, e2b = 0.f, e3a = 0.f, e3b = 0.f;

    for (int j0 = beg; j0 < end; j0 += 16) {
        unsigned p0 = csr[j0];
        unsigned p1 = (j0 + 1  < end) ? csr[j0 + 1]  : 0u;
        unsigned p2 = (j0 + 2  < end) ? csr[j0 + 2]  : 0u;
        unsigned p3 = (j0 + 3  < end) ? csr[j0 + 3]  : 0u;
        unsigned p4 = (j0 + 4  < end) ? csr[j0 + 4]  : 0u;
        unsigned p5 = (j0 + 5  < end) ? csr[j0 + 5]  : 0u;
        unsigned p6 = (j0 + 6  < end) ? csr[j0 + 6]  : 0u;
        unsigned p7 = (j0 + 7  < end) ? csr[j0 + 7]  : 0u;
        unsigned p8 = (j0 + 8  < end) ? csr[j0 + 8]  : 0u;
        unsigned p9 = (j0 + 9  < end) ? csr[j0 + 9]  : 0u;
        unsigned pa = (j0 + 10 < end) ? csr[j0 + 10] : 0u;
        unsigned pb = (j0 + 11 < end) ? csr[j0 + 11] : 0u;
        unsigned pc = (j0 + 12 < end) ? csr[j0 + 12] : 0u;
        unsigned pd = (j0 + 13 < end) ? csr[j0 + 13] : 0u;
        unsigned pe = (j0 + 14 < end) ? csr[j0 + 14] : 0u;
        unsigned pf = (j0 + 15 < end) ? csr[j0 + 15] : 0u;
        unsigned v0 = srcp[(size_t)(p0 >> 15) * 32 + c];
        unsigned v1 = srcp[(size_t)(p1 >> 15) * 32 + c];
        unsigned v2 = srcp[(size_t)(p2 >> 15) * 32 + c];
        unsigned v3 = srcp[(size_t)(p3 >> 15) * 32 + c];
        unsigned v4 = srcp[(size_t)(p4 >> 15) * 32 + c];
        unsigned v5 = srcp[(size_t)(p5 >> 15) * 32 + c];
        unsigned v6 = srcp[(size_t)(p6 >> 15) * 32 + c];
        unsigned v7 = srcp[(size_t)(p7 >> 15) * 32 + c];
        unsigned v8 = srcp[(size_t)(p8 >> 15) * 32 + c];
        unsigned v9 = srcp[(size_t)(p9 >> 15) * 32 + c];
        unsigned va = srcp[(size_t)(pa >> 15) * 32 + c];
        unsigned vb = srcp[(size_t)(pb >> 15) * 32 + c];
        unsigned vc = srcp[(size_t)(pc >> 15) * 32 + c];
        unsigned vd = srcp[(size_t)(pd >> 15) * 32 + c];
        unsigned ve = srcp[(size_t)(pe >> 15) * 32 + c];
        unsigned vf = srcp[(size_t)(pf >> 15) * 32 + c];
        float w0 = dec_w(p0), w1 = dec_w(p1), w2 = dec_w(p2), w3 = dec_w(p3);
        float w4 = dec_w(p4), w5 = dec_w(p5), w6 = dec_w(p6), w7 = dec_w(p7);
        float w8 = dec_w(p8), w9 = dec_w(p9), wa = dec_w(pa), wb = dec_w(pb);
        float wc = dec_w(pc), wd = dec_w(pd), we = dec_w(pe), wf = dec_w(pf);
        e0a += w0 * lo_bf(v0); e0b += w0 * hi_bf(v0);
        e1a += w1 * lo_bf(v1); e1b += w1 * hi_bf(v1);
        e2a += w2 * lo_bf(v2); e2b += w2 * hi_bf(v2);
        e3a += w3 * lo_bf(v3); e3b += w3 * hi_bf(v3);
        e0a += w4 * lo_bf(v4); e0b += w4 * hi_bf(v4);
        e1a += w5 * lo_bf(v5); e1b += w5 * hi_bf(v5);
        e2a += w6 * lo_bf(v6); e2b += w6 * hi_bf(v6);
        e3a += w7 * lo_bf(v7); e3b += w7 * hi_bf(v7);
        e0a += w8 * lo_bf(v8); e0b += w8 * hi_bf(v8);
        e1a += w9 * lo_bf(v9); e1b += w9 * hi_bf(v9);
        e2a += wa * lo_bf(va); e2b += wa * hi_bf(va);
        e3a += wb * lo_bf(vb); e3b += wb * hi_bf(vb);
        e0a += wc * lo_bf(vc); e0b += wc * hi_bf(vc);
        e1a += wd * lo_bf(vd); e1b += wd * hi_bf(vd);
        e2a += we * lo_bf(ve); e2b += we * hi_bf(ve);
        e3a += wf * lo_bf(vf); e3b += wf * hi_bf(vf);
    }
    float a0 = (e0a + e1a) + (e2a + e3a);
    float a1 = (e0b + e1b) + (e2b + e3b);

    if (FINAL) {
        float2 bb = ((const float2*)bias)[c];
        a0 = 1.0f / (1.0f + __expf(-(a0 + bb.x)));
        a1 = 1.0f / (1.0f + __expf(-(a1 + bb.y)));
        ((float2*)dst_f32)[(size_t)node * 32 + c] = make_float2(a0, a1);
    } else {
        ((unsigned*)dst_bf)[(size_t)node * 32 + c] = pack2bf(a0, a1);
    }
}

// ================= launch =================

static inline size_t align16(size_t x) { return (x + 15) & ~(size_t)15; }

extern "C" void kernel_launch(void* const* d_in, const int* in_sizes, int n_in,
                              void* d_out, int out_size, void* d_ws, size_t ws_size,
                              hipStream_t stream) {
    const float* x = (const float*)d_in[0];
    const int* edge_index = (const int*)d_in[1];
    const float* W = (const float*)d_in[2];
    const float* b = (const float*)d_in[3];
    float* out = (float*)d_out;

    const int N = N_NODES;
    const int E = in_sizes[1] / 2;

    const int* row = edge_index;        // source
    const int* col = edge_index + E;    // destination

    char* ws = (char*)d_ws;
    size_t off = 0;
    int* cnt = (int*)(ws + off);             off = align16(off + (size_t)N * 4);
    float* dinv = (float*)(ws + off);        off = align16(off + (size_t)N * 4);
    int* row_start = (int*)(ws + off);       off = align16(off + (size_t)(N + 1) * 4);
    int* partials = (int*)(ws + off);        off = align16(off + 512 * 4);
    unsigned* csr = (unsigned*)(ws + off);   off = align16(off + (size_t)E * 4);
    unsigned short* y0 = (unsigned short*)(ws + off); off = align16(off + (size_t)N * OUT_C * 2);
    unsigned short* y1 = (unsigned short*)(ws + off); off = align16(off + (size_t)N * OUT_C * 2);
    // eidx lifetime (count -> fill) is disjoint from y1 (gather1 -> gather2): alias.
    unsigned short* eidx = y1;

    const int B = 256;
    const int nb_e = (E + B - 1) / B;               // 3125
    const int nb_scan = (N + SCAN_B - 1) / SCAN_B;  // 196
    const int nb_lin = (N + 63) / 64;               // 1563
    int nbg = nb_lin;                                // groups of {2 fill, 1 linear}
    if (2 * nbg < nb_e) nbg = (nb_e + 1) / 2;

    // ---- CSR metadata ----
    hipMemsetAsync(cnt, 0, (size_t)N * 4, stream);
    count_kernel<<<nb_e, B, 0, stream>>>(col, cnt, eidx, E);
    scan_pass1_kernel<<<nb_scan, SCAN_B, 0, stream>>>(cnt, partials, N);
    scan23_kernel<<<nb_scan, SCAN_B, 0, stream>>>(cnt, partials, row_start, dinv, N, nb_scan);

    // ---- fused: csr_fill (atomic-free) + linear, interleaved 2:1 ----
    fill_linear_kernel<<<3 * nbg, B, 0, stream>>>(row, col, dinv, row_start, eidx, csr, E,
                                                  x, W, y0, N, nb_lin);

    // ---- hop 1 (8 nodes per 256-thread block) ----
    gather_kernel<false><<<(N + 7) / 8, B, 0, stream>>>(y0, y1, nullptr, row_start, csr, dinv, b, N);

    // ---- hop 2 + bias + sigmoid ----
    gather_kernel<true><<<(N + 7) / 8, B, 0, stream>>>(y1, nullptr, out, row_start, csr, dinv, b, N);
}

// Round 9
// 209.314 us; speedup vs baseline: 1.2750x; 1.0032x over previous
//
#include <hip/hip_runtime.h>
#include <hip/hip_bf16.h>
#include <math.h>

#define N_NODES 100000
#define N_EDGES 800000
#define IN_C 96
#define OUT_C 64
#define C4 (IN_C / 4)   // 24 float4 chunks per node
#define XPAD 104        // padded LDS row stride in bf16 elems
#define SCAN_B 512      // scan block width

typedef __attribute__((ext_vector_type(8))) short bf16x8;
typedef __attribute__((ext_vector_type(4))) float f32x4;

// bf16 helpers (manual, deterministic RNE)
__device__ __forceinline__ unsigned short f2bf(float f) {
    unsigned u = __float_as_uint(f);
    unsigned r = 0x7FFFu + ((u >> 16) & 1u);
    return (unsigned short)((u + r) >> 16);
}
__device__ __forceinline__ unsigned pack2bf(float a, float b) {
    return (unsigned)f2bf(a) | ((unsigned)f2bf(b) << 16);
}
// packed csr entry: [src:17][w_bf15:15]  (w in (0,1] so bf16 sign bit is 0)
__device__ __forceinline__ float dec_w(unsigned p) {
    return __uint_as_float((p & 0x7FFFu) << 16);
}
__device__ __forceinline__ float lo_bf(unsigned v) { return __uint_as_float(v << 16); }
__device__ __forceinline__ float hi_bf(unsigned v) { return __uint_as_float(v & 0xFFFF0000u); }

// ================= CSR build =================

// count in-degree AND record each edge's within-node slot (the atomic's return
// value) so the fill pass needs no second atomic.
__global__ void count_kernel(const int* __restrict__ col, int* __restrict__ cnt,
                             unsigned short* __restrict__ eidx, int e) {
    int i = blockIdx.x * blockDim.x + threadIdx.x;
    if (i < e) {
        int idx = atomicAdd(&cnt[col[i]], 1);
        eidx[i] = (unsigned short)idx;
    }
}

// per-512-block sums
__global__ void scan_pass1_kernel(const int* __restrict__ cnt, int* __restrict__ partials, int n) {
    __shared__ int s[SCAN_B];
    int i = blockIdx.x * SCAN_B + threadIdx.x;
    int v = (i < n) ? cnt[i] : 0;
    s[threadIdx.x] = v;
    __syncthreads();
    for (int off = SCAN_B / 2; off > 0; off >>= 1) {
        if (threadIdx.x < off) s[threadIdx.x] += s[threadIdx.x + off];
        __syncthreads();
    }
    if (threadIdx.x == 0) partials[blockIdx.x] = s[0];
}

// fused scan2+scan3: every block redundantly scans the partials (nparts<=512),
// then scans its own 512 cnt elements; writes row_start/dinv (+total).
__global__ void scan23_kernel(const int* __restrict__ cnt, const int* __restrict__ partials,
                              int* __restrict__ row_start, float* __restrict__ dinv,
                              int n, int nparts) {
    __shared__ int ps[SCAN_B];
    __shared__ int es[SCAN_B];
    int t = threadIdx.x;

    int pv = (t < nparts) ? partials[t] : 0;
    ps[t] = pv;
    __syncthreads();
    int run = pv;
    for (int off = 1; off < SCAN_B; off <<= 1) {
        int tmp = (t >= off) ? ps[t - off] : 0;
        __syncthreads();
        run += tmp;
        ps[t] = run;
        __syncthreads();
    }
    int total = ps[nparts - 1];
    __syncthreads();
    ps[t] = run - pv;   // exclusive
    __syncthreads();
    int block_off = ps[blockIdx.x];

    int i = blockIdx.x * SCAN_B + t;
    int v = (i < n) ? cnt[i] : 0;
    es[t] = v;
    __syncthreads();
    int erun = v;
    for (int off = 1; off < SCAN_B; off <<= 1) {
        int tmp = (t >= off) ? es[t - off] : 0;
        __syncthreads();
        erun += tmp;
        es[t] = erun;
        __syncthreads();
    }
    if (i < n) {
        int start = block_off + erun - v;   // exclusive
        row_start[i] = start;
        dinv[i] = rsqrtf((float)v + 1.0f);
    }
    if (blockIdx.x == 0 && t == 0) row_start[n] = total;
}

// ================= fused: csr_fill + linear, interleaved 2:1 =================
// blockIdx%3 in {0,1} -> fill block (atomic-free: pos = row_start[c]+eidx[i]);
// blockIdx%3 == 2     -> linear block (MFMA x@W^T, W staged in LDS, x loaded
//                        global->reg directly: only 13.3KB LDS -> 8 blocks/CU).

__global__ void fill_linear_kernel(const int* __restrict__ row, const int* __restrict__ col,
                                   const float* __restrict__ dinv,
                                   const int* __restrict__ row_start,
                                   const unsigned short* __restrict__ eidx,
                                   unsigned* __restrict__ csr, int e,
                                   const float* __restrict__ x, const float* __restrict__ W,
                                   unsigned short* __restrict__ y, int n, int nb_lin) {
    __shared__ unsigned short wbf[64 * XPAD];

    int g = blockIdx.x / 3;
    int r3 = blockIdx.x - g * 3;
    if (r3 != 2) {
        int i = (g * 2 + r3) * 256 + threadIdx.x;
        if (i < e) {
            int r = row[i];
            int c = col[i];
            float w = dinv[r] * dinv[c];
            int pos = row_start[c] + (int)eidx[i];
            csr[pos] = ((unsigned)r << 15) | (unsigned)f2bf(w);
        }
        return;
    }
    if (g >= nb_lin) return;

    int tid = threadIdx.x;
    int lane = tid & 63;
    int wv = tid >> 6;
    int node0 = g * 64;

    // stage W only (13.3KB)
    for (int i = tid; i < 64 * C4; i += 256) {
        int o = i / C4;
        int c4 = i - o * C4;
        float4 v = ((const float4*)(W + (size_t)o * IN_C))[c4];
        uint2 pk;
        pk.x = pack2bf(v.x, v.y);
        pk.y = pack2bf(v.z, v.w);
        *(uint2*)&wbf[o * XPAD + c4 * 4] = pk;
    }
    __syncthreads();

    int l16 = lane & 15;
    int quad = lane >> 4;

    // A-row for this lane: loaded straight from global (f32 -> bf16, same RNE)
    int arow = node0 + wv * 16 + l16;
    const float* xr = x + (size_t)((arow < n) ? arow : 0) * IN_C + quad * 8;

    f32x4 acc0 = {0.f, 0.f, 0.f, 0.f};
    f32x4 acc1 = {0.f, 0.f, 0.f, 0.f};
    f32x4 acc2 = {0.f, 0.f, 0.f, 0.f};
    f32x4 acc3 = {0.f, 0.f, 0.f, 0.f};

#pragma unroll
    for (int kc = 0; kc < 3; ++kc) {
        float4 v0 = ((const float4*)(xr + kc * 32))[0];
        float4 v1 = ((const float4*)(xr + kc * 32))[1];
        union { bf16x8 v; unsigned u[4]; } au;
        au.u[0] = pack2bf(v0.x, v0.y);
        au.u[1] = pack2bf(v0.z, v0.w);
        au.u[2] = pack2bf(v1.x, v1.y);
        au.u[3] = pack2bf(v1.z, v1.w);
        bf16x8 a = au.v;
        bf16x8 b0 = *(const bf16x8*)&wbf[(0 * 16 + l16) * XPAD + kc * 32 + quad * 8];
        bf16x8 b1 = *(const bf16x8*)&wbf[(1 * 16 + l16) * XPAD + kc * 32 + quad * 8];
        bf16x8 b2 = *(const bf16x8*)&wbf[(2 * 16 + l16) * XPAD + kc * 32 + quad * 8];
        bf16x8 b3 = *(const bf16x8*)&wbf[(3 * 16 + l16) * XPAD + kc * 32 + quad * 8];
        acc0 = __builtin_amdgcn_mfma_f32_16x16x32_bf16(a, b0, acc0, 0, 0, 0);
        acc1 = __builtin_amdgcn_mfma_f32_16x16x32_bf16(a, b1, acc1, 0, 0, 0);
        acc2 = __builtin_amdgcn_mfma_f32_16x16x32_bf16(a, b2, acc2, 0, 0, 0);
        acc3 = __builtin_amdgcn_mfma_f32_16x16x32_bf16(a, b3, acc3, 0, 0, 0);
    }

#pragma unroll
    for (int r = 0; r < 4; ++r) {
        int node = node0 + wv * 16 + quad * 4 + r;
        if (node < n) {
            size_t base = (size_t)node * OUT_C + l16;
            y[base + 0]  = f2bf(acc0[r]);
            y[base + 16] = f2bf(acc1[r]);
            y[base + 32] = f2bf(acc2[r]);
            y[base + 48] = f2bf(acc3[r]);
        }
    }
}

// ================= gather hop: 16 lanes per node (uint2), 4 nodes per wave =================
// Lane c (0..15) of each 16-lane group owns dwords 2c,2c+1 (channels 4c..4c+3)
// of its node's 128B row -> uint2 loads keep the per-slot row read fully
// coalesced (16 lanes x 8B = 128B) while packing 4 nodes per wave. Total VALU
// per wave unchanged vs 2-nodes/wave (4 ch/lane instead of 2); wave count
// halves -> half the exposed row_start->csr->src latency chains.
// 16 predicated slots per iteration (invalid slot -> p=0 -> w=+0.0, src node 0,
// contributes exactly 0): deg<=16 (99.7% at Poisson-8) finishes in one
// iteration. Per-channel accumulation order identical to the 2-node layout
// (slot k -> bank k&3), so results are bit-identical.

template <bool FINAL>
__global__ void gather_kernel(const unsigned short* __restrict__ src,
                              unsigned short* __restrict__ dst_bf,
                              float* __restrict__ dst_f32,
                              const int* __restrict__ row_start, const unsigned* __restrict__ csr,
                              const float* __restrict__ dinv, const float* __restrict__ bias,
                              int n) {
    int node = blockIdx.x * (blockDim.x >> 4) + (threadIdx.x >> 4);
    if (node >= n) return;
    int c = threadIdx.x & 15;                // dwords 2c, 2c+1
    const uint2* srcp = (const uint2*)src;

    int beg = row_start[node];
    int end = row_start[node + 1];

    // self-loop
    uint2 pv = srcp[(size_t)node * 16 + c];
    float s = dinv[node];
    float ss = s * s;

    float e0a = ss * lo_bf(pv.x), e0b = ss * hi_bf(pv.x);
    float e0c = ss * lo_bf(pv.y), e0d = ss * hi_bf(pv.y);
    float e1a = 0.f, e1b = 0.f, e1c = 0.f, e1d = 0.f;
    float e2a = 0.f, e2b = 0.f, e2c = 0.f, e2d = 0.f;
    float e3a = 0.f, e3b = 0.f, e3c = 0.f, e3d = 0.f;

    for (int j0 = beg; j0 < end; j0 += 16) {
        unsigned p0 = csr[j0];
        unsigned p1 = (j0 + 1  < end) ? csr[j0 + 1]  : 0u;
        unsigned p2 = (j0 + 2  < end) ? csr[j0 + 2]  : 0u;
        unsigned p3 = (j0 + 3  < end) ? csr[j0 + 3]  : 0u;
        unsigned p4 = (j0 + 4  < end) ? csr[j0 + 4]  : 0u;
        unsigned p5 = (j0 + 5  < end) ? csr[j0 + 5]  : 0u;
        unsigned p6 = (j0 + 6  < end) ? csr[j0 + 6]  : 0u;
        unsigned p7 = (j0 + 7  < end) ? csr[j0 + 7]  : 0u;
        unsigned p8 = (j0 + 8  < end) ? csr[j0 + 8]  : 0u;
        unsigned p9 = (j0 + 9  < end) ? csr[j0 + 9]  : 0u;
        unsigned pa = (j0 + 10 < end) ? csr[j0 + 10] : 0u;
        unsigned pb = (j0 + 11 < end) ? csr[j0 + 11] : 0u;
        unsigned pc = (j0 + 12 < end) ? csr[j0 + 12] : 0u;
        unsigned pd = (j0 + 13 < end) ? csr[j0 + 13] : 0u;
        unsigned pe = (j0 + 14 < end) ? csr[j0 + 14] : 0u;
        unsigned pf = (j0 + 15 < end) ? csr[j0 + 15] : 0u;
        uint2 v0 = srcp[(size_t)(p0 >> 15) * 16 + c];
        uint2 v1 = srcp[(size_t)(p1 >> 15) * 16 + c];
        uint2 v2 = srcp[(size_t)(p2 >> 15) * 16 + c];
        uint2 v3 = srcp[(size_t)(p3 >> 15) * 16 + c];
        uint2 v4 = srcp[(size_t)(p4 >> 15) * 16 + c];
        uint2 v5 = srcp[(size_t)(p5 >> 15) * 16 + c];
        uint2 v6 = srcp[(size_t)(p6 >> 15) * 16 + c];
        uint2 v7 = srcp[(size_t)(p7 >> 15) * 16 + c];
        uint2 v8 = srcp[(size_t)(p8 >> 15) * 16 + c];
        uint2 v9 = srcp[(size_t)(p9 >> 15) * 16 + c];
        uint2 va = srcp[(size_t)(pa >> 15) * 16 + c];
        uint2 vb = srcp[(size_t)(pb >> 15) * 16 + c];
        uint2 vc = srcp[(size_t)(pc >> 15) * 16 + c];
        uint2 vd = srcp[(size_t)(pd >> 15) * 16 + c];
        uint2 ve = srcp[(size_t)(pe >> 15) * 16 + c];
        uint2 vf = srcp[(size_t)(pf >> 15) * 16 + c];
        float w0 = dec_w(p0), w1 = dec_w(p1), w2 = dec_w(p2), w3 = dec_w(p3);
        float w4 = dec_w(p4), w5 = dec_w(p5), w6 = dec_w(p6), w7 = dec_w(p7);
        float w8 = dec_w(p8), w9 = dec_w(p9), wa = dec_w(pa), wb = dec_w(pb);
        float wc = dec_w(pc), wd = dec_w(pd), we = dec_w(pe), wf = dec_w(pf);
        e0a += w0 * lo_bf(v0.x); e0b += w0 * hi_bf(v0.x); e0c += w0 * lo_bf(v0.y); e0d += w0 * hi_bf(v0.y);
        e1a += w1 * lo_bf(v1.x); e1b += w1 * hi_bf(v1.x); e1c += w1 * lo_bf(v1.y); e1d += w1 * hi_bf(v1.y);
        e2a += w2 * lo_bf(v2.x); e2b += w2 * hi_bf(v2.x); e2c += w2 * lo_bf(v2.y); e2d += w2 * hi_bf(v2.y);
        e3a += w3 * lo_bf(v3.x); e3b += w3 * hi_bf(v3.x); e3c += w3 * lo_bf(v3.y); e3d += w3 * hi_bf(v3.y);
        e0a += w4 * lo_bf(v4.x); e0b += w4 * hi_bf(v4.x); e0c += w4 * lo_bf(v4.y); e0d += w4 * hi_bf(v4.y);
        e1a += w5 * lo_bf(v5.x); e1b += w5 * hi_bf(v5.x); e1c += w5 * lo_bf(v5.y); e1d += w5 * hi_bf(v5.y);
        e2a += w6 * lo_bf(v6.x); e2b += w6 * hi_bf(v6.x); e2c += w6 * lo_bf(v6.y); e2d += w6 * hi_bf(v6.y);
        e3a += w7 * lo_bf(v7.x); e3b += w7 * hi_bf(v7.x); e3c += w7 * lo_bf(v7.y); e3d += w7 * hi_bf(v7.y);
        e0a += w8 * lo_bf(v8.x); e0b += w8 * hi_bf(v8.x); e0c += w8 * lo_bf(v8.y); e0d += w8 * hi_bf(v8.y);
        e1a += w9 * lo_bf(v9.x); e1b += w9 * hi_bf(v9.x); e1c += w9 * lo_bf(v9.y); e1d += w9 * hi_bf(v9.y);
        e2a += wa * lo_bf(va.x); e2b += wa * hi_bf(va.x); e2c += wa * lo_bf(va.y); e2d += wa * hi_bf(va.y);
        e3a += wb * lo_bf(vb.x); e3b += wb * hi_bf(vb.x); e3c += wb * lo_bf(vb.y); e3d += wb * hi_bf(vb.y);
        e0a += wc * lo_bf(vc.x); e0b += wc * hi_bf(vc.x); e0c += wc * lo_bf(vc.y); e0d += wc * hi_bf(vc.y);
        e1a += wd * lo_bf(vd.x); e1b += wd * hi_bf(vd.x); e1c += wd * lo_bf(vd.y); e1d += wd * hi_bf(vd.y);
        e2a += we * lo_bf(ve.x); e2b += we * hi_bf(ve.x); e2c += we * lo_bf(ve.y); e2d += we * hi_bf(ve.y);
        e3a += wf * lo_bf(vf.x); e3b += wf * hi_bf(vf.x); e3c += wf * lo_bf(vf.y); e3d += wf * hi_bf(vf.y);
    }
    float a0 = (e0a + e1a) + (e2a + e3a);
    float a1 = (e0b + e1b) + (e2b + e3b);
    float a2 = (e0c + e1c) + (e2c + e3c);
    float a3 = (e0d + e1d) + (e2d + e3d);

    if (FINAL) {
        float4 bb = ((const float4*)bias)[c];
        float4 o;
        o.x = 1.0f / (1.0f + __expf(-(a0 + bb.x)));
        o.y = 1.0f / (1.0f + __expf(-(a1 + bb.y)));
        o.z = 1.0f / (1.0f + __expf(-(a2 + bb.z)));
        o.w = 1.0f / (1.0f + __expf(-(a3 + bb.w)));
        ((float4*)dst_f32)[(size_t)node * 16 + c] = o;
    } else {
        uint2 o;
        o.x = pack2bf(a0, a1);
        o.y = pack2bf(a2, a3);
        ((uint2*)dst_bf)[(size_t)node * 16 + c] = o;
    }
}

// ================= launch =================

static inline size_t align16(size_t x) { return (x + 15) & ~(size_t)15; }

extern "C" void kernel_launch(void* const* d_in, const int* in_sizes, int n_in,
                              void* d_out, int out_size, void* d_ws, size_t ws_size,
                              hipStream_t stream) {
    const float* x = (const float*)d_in[0];
    const int* edge_index = (const int*)d_in[1];
    const float* W = (const float*)d_in[2];
    const float* b = (const float*)d_in[3];
    float* out = (float*)d_out;

    const int N = N_NODES;
    const int E = in_sizes[1] / 2;

    const int* row = edge_index;        // source
    const int* col = edge_index + E;    // destination

    char* ws = (char*)d_ws;
    size_t off = 0;
    int* cnt = (int*)(ws + off);             off = align16(off + (size_t)N * 4);
    float* dinv = (float*)(ws + off);        off = align16(off + (size_t)N * 4);
    int* row_start = (int*)(ws + off);       off = align16(off + (size_t)(N + 1) * 4);
    int* partials = (int*)(ws + off);        off = align16(off + 512 * 4);
    unsigned* csr = (unsigned*)(ws + off);   off = align16(off + (size_t)E * 4);
    unsigned short* y0 = (unsigned short*)(ws + off); off = align16(off + (size_t)N * OUT_C * 2);
    unsigned short* y1 = (unsigned short*)(ws + off); off = align16(off + (size_t)N * OUT_C * 2);
    // eidx lifetime (count -> fill) is disjoint from y1 (gather1 -> gather2): alias.
    unsigned short* eidx = y1;

    const int B = 256;
    const int nb_e = (E + B - 1) / B;               // 3125
    const int nb_scan = (N + SCAN_B - 1) / SCAN_B;  // 196
    const int nb_lin = (N + 63) / 64;               // 1563
    int nbg = nb_lin;                                // groups of {2 fill, 1 linear}
    if (2 * nbg < nb_e) nbg = (nb_e + 1) / 2;

    // ---- CSR metadata ----
    hipMemsetAsync(cnt, 0, (size_t)N * 4, stream);
    count_kernel<<<nb_e, B, 0, stream>>>(col, cnt, eidx, E);
    scan_pass1_kernel<<<nb_scan, SCAN_B, 0, stream>>>(cnt, partials, N);
    scan23_kernel<<<nb_scan, SCAN_B, 0, stream>>>(cnt, partials, row_start, dinv, N, nb_scan);

    // ---- fused: csr_fill (atomic-free) + linear, interleaved 2:1 ----
    fill_linear_kernel<<<3 * nbg, B, 0, stream>>>(row, col, dinv, row_start, eidx, csr, E,
                                                  x, W, y0, N, nb_lin);

    // ---- hop 1 (16 nodes per 256-thread block) ----
    gather_kernel<false><<<(N + 15) / 16, B, 0, stream>>>(y0, y1, nullptr, row_start, csr, dinv, b, N);

    // ---- hop 2 + bias + sigmoid ----
    gather_kernel<true><<<(N + 15) / 16, B, 0, stream>>>(y1, nullptr, out, row_start, csr, dinv, b, N);
}